// Round 6
// baseline (1191.350 us; speedup 1.0000x reference)
//
#include <hip/hip_runtime.h>

#define EPS_ 1e-5f

typedef __attribute__((ext_vector_type(8))) short bf16x8;
typedef __attribute__((ext_vector_type(8))) unsigned short u16x8;
typedef __attribute__((ext_vector_type(4))) float f32x4;
typedef __attribute__((address_space(3))) u16x8 lds_u16x8;
typedef __attribute__((address_space(3))) f32x4 lds_f32x4;

__device__ __forceinline__ float sigmoidf_(float v) { return 1.f / (1.f + __expf(-v)); }

__device__ __forceinline__ unsigned short f2bf(float f) {
  unsigned int u = __float_as_uint(f);
  u += 0x7fff + ((u >> 16) & 1);  // RNE
  return (unsigned short)(u >> 16);
}

__device__ __forceinline__ void cvt8_(u16x8 v, float* f) {
  union { u16x8 s; unsigned int u[4]; } uu;
  uu.s = v;
#pragma unroll
  for (int j = 0; j < 4; ++j) {
    f[2 * j] = __uint_as_float(uu.u[j] << 16);
    f[2 * j + 1] = __uint_as_float(uu.u[j] & 0xffff0000u);
  }
}

// async global->LDS, 16B per lane; LDS dest is wave-uniform base + lane*16
__device__ __forceinline__ void gload16(const void* g, void* l) {
  __builtin_amdgcn_global_load_lds((const __attribute__((address_space(1))) unsigned int*)(g),
                                   (__attribute__((address_space(3))) unsigned int*)(l), 16, 0, 0);
}

// ---------------------------------------------------------------- gate stage 2
__global__ void gate_kernel(const float* __restrict__ partial, const float* __restrict__ gw,
                            const float* __restrict__ gb, float* __restrict__ gout) {
  int b = blockIdx.x, t = threadIdx.x;
  float s = partial[b * 256 + t] * gw[t];
#pragma unroll
  for (int off = 32; off; off >>= 1) s += __shfl_down(s, off, 64);
  __shared__ float red[4];
  if ((t & 63) == 0) red[t >> 6] = s;
  __syncthreads();
  if (t == 0) {
    float tot = (red[0] + red[1]) + (red[2] + red[3]);
    gout[b] = sigmoidf_(tot * (1.f / 16384.f) + gb[0]);
  }
}

// ---------------------------------------------------------------- weight transform (dense conv)
__global__ void wtrans_kernel(const float* __restrict__ w, unsigned short* __restrict__ wT) {
  int n = blockIdx.x * 256 + threadIdx.x;  // 589824
  int c = n & 31, oc = (n >> 5) & 255, t9 = n >> 13;
  int cb = t9 / 9, tap = t9 - cb * 9;
  wT[n] = f2bf(w[(oc * 256 + cb * 32 + c) * 9 + tap]);
}

// ---------------------------------------------------------------- kernelgen weight prep
// w1f: [g=32][tp=9][o=8][ic=8] fp32, BN-scale folded in.
// b1f: [c=256] BN-folded bias.  w2t: [c=256][28] (n<25 valid) transposed 1x1 weights.
// zb: 16 floats (64B) of zeros — halo source for conv_mfma's global_load_lds.
__global__ void kprep_kernel(const float* __restrict__ w1, const float* __restrict__ b1,
                             const float* __restrict__ bng, const float* __restrict__ bnb,
                             const float* __restrict__ bnm, const float* __restrict__ bnv,
                             const float* __restrict__ w2, float* __restrict__ w1f,
                             float* __restrict__ b1f, float* __restrict__ w2t,
                             float* __restrict__ zb) {
  int n = blockIdx.x * 256 + threadIdx.x;  // 72 blocks -> 18432 threads
  if (n < 16) zb[n] = 0.f;
  if (n < 256) {
    float s = bng[n] * rsqrtf(bnv[n] + EPS_);
    b1f[n] = (b1[n] - bnm[n]) * s + bnb[n];
  }
  if (n < 18432) {
    int ic = n & 7, o = (n >> 3) & 7, tp = (n >> 6) % 9, g = n / 576;
    int c = g * 8 + o;
    float s = bng[c] * rsqrtf(bnv[c] + EPS_);
    w1f[n] = w1[c * 72 + ic * 9 + tp] * s;
  }
  if (n < 7168) {
    int nn = n % 28, c = n / 28;
    w2t[n] = (nn < 25) ? w2[nn * 256 + c] : 0.f;
  }
}

// ---------------------------------------------------------------- x fp32 NCHW -> xT bf16 NHWC
// + fused GAP partial sums (atomicAdd into partial[b*256+ch]; saves a full x re-read).
// grid: 256 px-tiles(64) x 8 b = 2048 blocks
__global__ __launch_bounds__(256) void transpose_kernel(const float* __restrict__ x,
                                                        unsigned short* __restrict__ xT,
                                                        float* __restrict__ partial) {
  int blk = blockIdx.x;
  int tile = blk & 255, b = blk >> 8;
  int px0 = tile * 64;
  __shared__ unsigned int tr[64 * 130];  // [px][128 ch-pair words + 2 pad]
  for (int i = threadIdx.x; i < 1024; i += 256) {
    int ch2 = i >> 3, pc = i & 7;
    const float* p0 = x + (((size_t)b * 256 + ch2 * 2) << 14) + px0 + pc * 8;
    const float4* a4 = (const float4*)p0;
    const float4* b4 = (const float4*)(p0 + 16384);
    float4 a0 = a4[0], a1 = a4[1], b0 = b4[0], b1 = b4[1];
    float fa[8] = {a0.x, a0.y, a0.z, a0.w, a1.x, a1.y, a1.z, a1.w};
    float fb[8] = {b0.x, b0.y, b0.z, b0.w, b1.x, b1.y, b1.z, b1.w};
    float sa = 0.f, sb = 0.f;
#pragma unroll
    for (int j = 0; j < 8; ++j) {
      sa += fa[j];
      sb += fb[j];
      unsigned int w = (unsigned int)f2bf(fa[j]) | ((unsigned int)f2bf(fb[j]) << 16);
      tr[(pc * 8 + j) * 130 + ch2] = w;
    }
    // 8-lane group reduce (lanes pc=0..7 share ch2), then one atomic per channel
    sa += __shfl_down(sa, 4, 8); sa += __shfl_down(sa, 2, 8); sa += __shfl_down(sa, 1, 8);
    sb += __shfl_down(sb, 4, 8); sb += __shfl_down(sb, 2, 8); sb += __shfl_down(sb, 1, 8);
    if ((threadIdx.x & 7) == 0) {
      atomicAdd(&partial[(b << 8) + ch2 * 2], sa);
      atomicAdd(&partial[(b << 8) + ch2 * 2 + 1], sb);
    }
  }
  __syncthreads();
  for (int i = threadIdx.x; i < 2048; i += 256) {
    int px = i >> 5, kc = i & 31;
    uint4 v = *(uint4*)&tr[px * 130 + kc * 4];
    *(uint4*)(xT + ((((size_t)b << 14)) + px0 + px) * 256 + kc * 8) = v;
  }
}

// ------------------- fused: grouped conv (BN pre-folded) + SiLU + 1x1 -> partial acc
// grid: 64 tiles(16x16) x 8 b x 4 splits = 2048 blocks; each block does 2 of 8 ch rounds.
__global__ __launch_bounds__(256, 6) void kernelgen_kernel(
    const unsigned short* __restrict__ xT, const float* __restrict__ w1f,
    const float* __restrict__ b1f, const float* __restrict__ w2t, float* __restrict__ pacc) {
  int blk = blockIdx.x;
  int split = blk >> 9;
  int low = blk & 511;
  int t = low & 63, b = low >> 6;
  int px0 = (t & 7) * 16, py0 = (t >> 3) * 16;
  int lx = threadIdx.x & 15, ly = threadIdx.x >> 4;
  __shared__ unsigned short xs[324 * 40];  // [18x18 px][32 ch + 8 pad]
  float acc[25];
#pragma unroll
  for (int n = 0; n < 25; ++n) acc[n] = 0.f;

#pragma unroll 1
  for (int gi = 0; gi < 2; ++gi) {  // 2 rounds of 4 groups (32 ch) each
    int gq = split * 2 + gi;
    __syncthreads();
    for (int i = threadIdx.x; i < 1296; i += 256) {
      int s = i & 3, p = i >> 2;
      int yy = py0 + p / 18 - 1, xx = px0 + (p % 18) - 1;
      u16x8 v = (u16x8)(unsigned short)0;
      if (((unsigned)yy < 128u) && ((unsigned)xx < 128u))
        v = *(const u16x8*)(xT + (((size_t)(b << 14)) + yy * 128 + xx) * 256 + gq * 32 + s * 8);
      *(lds_u16x8*)(&xs[p * 40 + s * 8]) = v;
    }
    __syncthreads();
#pragma unroll
    for (int s = 0; s < 4; ++s) {
      int g = gq * 4 + s;
      const float* wg = w1f + g * 576;  // [tp][o][ic], wave-uniform -> s_load
      const float* bp = b1f + g * 8;
      float h[8];
#pragma unroll
      for (int o = 0; o < 8; ++o) h[o] = bp[o];
#pragma unroll
      for (int tp = 0; tp < 9; ++tp) {
        float xv[8];
        u16x8 v = *(lds_u16x8*)(&xs[((ly + tp / 3) * 18 + lx + tp % 3) * 40 + s * 8]);
        cvt8_(v, xv);
        const float* wt = wg + tp * 64;
#pragma unroll
        for (int o = 0; o < 8; ++o)
#pragma unroll
          for (int ic = 0; ic < 8; ++ic) h[o] = fmaf(xv[ic], wt[o * 8 + ic], h[o]);
      }
#pragma unroll
      for (int o = 0; o < 8; ++o) {
        float sv = h[o] * sigmoidf_(h[o]);
        const float* w2p = w2t + (g * 8 + o) * 28;  // 25 contiguous floats
#pragma unroll
        for (int n = 0; n < 25; ++n) acc[n] = fmaf(sv, w2p[n], acc[n]);
      }
    }
  }
  size_t base = (((size_t)(b * 4 + split) * 25) << 14) + (py0 + ly) * 128 + px0 + lx;
#pragma unroll
  for (int n = 0; n < 25; ++n) pacc[base + ((size_t)n << 14)] = acc[n];
}

// ---------------------------------------------------------------- combine splits + softmax
__global__ __launch_bounds__(256) void kcombine_kernel(const float* __restrict__ pacc,
                                                       const float* __restrict__ b2,
                                                       float* __restrict__ kern) {
  int pix = blockIdx.x * 256 + threadIdx.x;  // 131072
  int b = pix >> 14, p = pix & 16383;
  float a[25];
#pragma unroll
  for (int n = 0; n < 25; ++n) a[n] = b2[n];
#pragma unroll
  for (int s = 0; s < 4; ++s) {
    const float* pp = pacc + (((size_t)(b * 4 + s) * 25) << 14) + p;
#pragma unroll
    for (int n = 0; n < 25; ++n) a[n] += pp[(size_t)n << 14];
  }
  float m = a[0];
#pragma unroll
  for (int n = 1; n < 25; ++n) m = fmaxf(m, a[n]);
  float sum = 0.f;
#pragma unroll
  for (int n = 0; n < 25; ++n) { a[n] = __expf(a[n] - m); sum += a[n]; }
  float inv = 1.f / sum;
  size_t base = (((size_t)b * 25) << 14) + p;
#pragma unroll
  for (int n = 0; n < 25; ++n) kern[base + ((size_t)n << 14)] = a[n] * inv;
}

// ---------------------------------------------------------------- dense conv via MFMA
// M=128 px (one row) x N=128 oc; K = 24 rows (8 cb x 3 kh) x 32 ch.
// ROW-GRANULAR RING-3 PIPELINE: 3 slots x 8320B = 24,960B LDS -> 6 blocks/CU at
// 4 waves each (24 waves/CU, 6/SIMD; VGPR<=85 via launch_bounds(256,6)).
// Per row R: [vmcnt(6): rows R+1,R+2 in flight, row R landed (in-order retirement)]
// [barrier] [3 taps x 16 MFMA, setprio(1)] [barrier] [stage row R+3 into slot R%3].
// Tail: vmcnt(3) at R=22, vmcnt(0) at R=23.
// Swizzle s = k ^ ((px>>1)&3) on the source; linear DMA dest; swizzled read.
// bid XCD-swizzle: each XCD gets 256 consecutive logical blocks (one batch image).
__global__ __launch_bounds__(256, 6) void conv_mfma_kernel(
    const unsigned short* __restrict__ xT, const unsigned short* __restrict__ wT,
    const float* __restrict__ bb, const float* __restrict__ bng, const float* __restrict__ bnb,
    const float* __restrict__ bnm, const float* __restrict__ bnv,
    const unsigned short* __restrict__ zbuf, float* __restrict__ out) {
  int nb = ((blockIdx.x & 7) << 8) | (blockIdx.x >> 3);  // XCD swizzle (2048 % 8 == 0)
  int ocb = nb & 1, y = (nb >> 1) & 127, b = nb >> 8;
  int tid = threadIdx.x, lane = tid & 63, wid = tid >> 6;
  int wy = wid >> 1, wx = wid & 1;
  int m_l = lane & 15, kgrp = lane >> 4;

  __shared__ char smem[24960];  // ring: 3 x 8320B row slots; epilogue sbuf 32x132x4=16896B
  unsigned short* xs = (unsigned short*)smem;
  float* sbuf = (float*)smem;
  const char* zc = (const char*)zbuf;

  // per-thread staging constants: wave w covers granules [w*130, w*130+130)
  int g0 = wid * 130 + lane, g1 = g0 + 64, g2 = wid * 130 + 128 + lane;  // g2: lane<2
  int px0_ = g0 >> 2, k0_ = g0 & 3, s0_ = k0_ ^ ((px0_ >> 1) & 3), gx0 = px0_ - 1;
  int px1_ = g1 >> 2, k1_ = g1 & 3, s1_ = k1_ ^ ((px1_ >> 1) & 3), gx1 = px1_ - 1;
  int px2_ = g2 >> 2, k2_ = g2 & 3, s2_ = k2_ ^ ((px2_ >> 1) & 3), gx2 = px2_ - 1;
  bool ok0 = (unsigned)gx0 < 128u, ok1 = (unsigned)gx1 < 128u, ok2 = (unsigned)gx2 < 128u;
  int off0 = gx0 * 512 + s0_ * 16, off1 = gx1 * 512 + s1_ * 16, off2 = gx2 * 512 + s2_ * 16;
  int d0 = (wid * 130) * 16, d1 = d0 + 1024, d2 = d0 + 2048;  // wave-uniform LDS bases

#define STAGE_ROW(slotB_, cbn_, khn_)                                                       \
  do {                                                                                      \
    int gy_ = y + (khn_)-1;                                                                 \
    bool gyok_ = ((unsigned)gy_ < 128u);                                                    \
    const char* rb_ =                                                                       \
        (const char*)xT + (((size_t)b << 14) + (size_t)(gy_ & 127) * 128) * 512 + (cbn_)*64;\
    gload16((gyok_ && ok0) ? rb_ + off0 : zc, smem + (slotB_) + d0);                        \
    gload16((gyok_ && ok1) ? rb_ + off1 : zc, smem + (slotB_) + d1);                        \
    if (lane < 2) gload16((gyok_ && ok2) ? rb_ + off2 : zc, smem + (slotB_) + d2);          \
  } while (0)

  f32x4 acc[4][4];
#pragma unroll
  for (int mt = 0; mt < 4; ++mt)
#pragma unroll
    for (int nt = 0; nt < 4; ++nt) acc[mt][nt] = (f32x4)0.f;

  // prologue: stage rows 0..2 (cb = R/3, kh = R%3)
  STAGE_ROW(0, 0, 0);
  STAGE_ROW(8320, 0, 1);
  STAGE_ROW(16640, 0, 2);

  // per-thread bfrag base offset (ushorts); row R tap kw lives at +(R*3+kw)*8192
  const unsigned short* wTb = wT + ((size_t)(ocb * 128 + wx * 64 + m_l) * 32 + kgrp * 8);
  int wybase = wy * 64;
  int khn = 0, cbn = 1;  // row R+3 starting at R=0 -> row 3 = cb1,kh0
  int slot = 0;          // R % 3

#pragma unroll 1
  for (int R = 0; R < 24; ++R) {
    if (R < 22) {
      asm volatile("s_waitcnt vmcnt(6)" ::: "memory");  // row R landed; R+1,R+2 in flight
    } else if (R == 22) {
      asm volatile("s_waitcnt vmcnt(3)" ::: "memory");
    } else {
      asm volatile("s_waitcnt vmcnt(0)" ::: "memory");
    }
    __builtin_amdgcn_s_barrier();
    asm volatile("" ::: "memory");
    const unsigned short* xb = xs + slot * 4160;
    __builtin_amdgcn_s_setprio(1);
#pragma unroll
    for (int kw = 0; kw < 3; ++kw) {
      bf16x8 bfrag[4];
      const unsigned short* wb = wTb + (size_t)(R * 3 + kw) * 8192;
#pragma unroll
      for (int nt = 0; nt < 4; ++nt) bfrag[nt] = *(const bf16x8*)(wb + nt * 512);
#pragma unroll
      for (int mt = 0; mt < 4; ++mt) {
        int apx = wybase + mt * 16 + m_l + kw;
        int kk = kgrp ^ ((apx >> 1) & 3);
        bf16x8 af =
            *(__attribute__((address_space(3))) bf16x8*)(&xb[apx * 32 + kk * 8]);
#pragma unroll
        for (int nt = 0; nt < 4; ++nt)
          acc[mt][nt] =
              __builtin_amdgcn_mfma_f32_16x16x32_bf16(af, bfrag[nt], acc[mt][nt], 0, 0, 0);
      }
    }
    __builtin_amdgcn_s_setprio(0);
    __builtin_amdgcn_s_barrier();  // slot R%3 free
    asm volatile("" ::: "memory");
    if (R < 21) {
      STAGE_ROW((size_t)slot * 8320, cbn, khn);
      ++khn;
      if (khn == 3) { khn = 0; ++cbn; }
    }
    slot = (slot == 2) ? 0 : slot + 1;
  }
#undef STAGE_ROW

  float scale4[4], bias4[4];
#pragma unroll
  for (int nt = 0; nt < 4; ++nt) {
    int oc = ocb * 128 + wx * 64 + nt * 16 + m_l;
    float s = bng[oc] * rsqrtf(bnv[oc] + EPS_);
    scale4[nt] = s;
    bias4[nt] = bnb[oc] + (bb[oc] - bnm[oc]) * s;
  }

  // epilogue: 4 passes of 32 oc through a 16,896B LDS transpose buffer
#pragma unroll
  for (int q = 0; q < 4; ++q) {
    __syncthreads();
    if (wx == (q >> 1)) {
#pragma unroll
      for (int half = 0; half < 2; ++half) {
        int nt = (q & 1) * 2 + half;
#pragma unroll
        for (int mt = 0; mt < 4; ++mt) {
          f32x4 v = acc[mt][nt];
          float o4[4];
#pragma unroll
          for (int r = 0; r < 4; ++r) {
            float hv = v[r] * scale4[nt] + bias4[nt];
            o4[r] = hv * sigmoidf_(hv);
          }
          int px = wybase + mt * 16 + kgrp * 4;
          *(lds_f32x4*)(&sbuf[(half * 16 + m_l) * 132 + px]) = (f32x4){o4[0], o4[1], o4[2], o4[3]};
        }
      }
    }
    __syncthreads();
    int kc = tid & 31, oc0 = tid >> 5;
#pragma unroll
    for (int i = 0; i < 4; ++i) {
      int ocl = oc0 + i * 8;
      f32x4 v = *(lds_f32x4*)(&sbuf[ocl * 132 + kc * 4]);
      *(f32x4*)(out + (((size_t)(b * 256 + ocb * 128 + q * 32 + ocl)) << 14) + y * 128 + kc * 4) =
          v;
    }
  }
}

// ---------------------------------------------------------------- CARAFE + blend (RMW on out)
// grid: 16 ch-groups x 8 bx x 4 by x 8 b = 4096 blocks; tile 16ch x 32y x 16x
__global__ __launch_bounds__(256) void carafe_blend_kernel(
    const unsigned short* __restrict__ xT, const float* __restrict__ kern,
    const float* __restrict__ gq, float* __restrict__ out) {
  int blk = blockIdx.x;
  int ocg = blk & 15, bx = (blk >> 4) & 7, by = (blk >> 7) & 3, b = blk >> 9;
  __shared__ unsigned short xc[720 * 16];  // [36x20 px][16 ch]
  for (int i = threadIdx.x; i < 1440; i += 256) {
    int half = i & 1, p = i >> 1;
    int py = p / 20, pxx = p - py * 20;
    int yy = by * 32 + py - 2, xx = bx * 16 + pxx - 2;
    yy = yy < 0 ? -yy : (yy > 127 ? 254 - yy : yy);
    xx = xx < 0 ? -xx : (xx > 127 ? 254 - xx : xx);
    *(lds_u16x8*)(&xc[p * 16 + half * 8]) =
        *(const u16x8*)(xT + (((size_t)(b << 14)) + yy * 128 + xx) * 256 + ocg * 16 + half * 8);
  }
  __syncthreads();
  int lx = threadIdx.x & 15, y0 = (threadIdx.x >> 4) * 2;
  float gv = gq[b];
  int gy0 = by * 32 + y0, gx = bx * 16 + lx;
  float kv0[25], kv1[25];
  size_t kb = (((size_t)b * 25) << 14) + gy0 * 128 + gx;
#pragma unroll
  for (int n = 0; n < 25; ++n) {
    kv0[n] = kern[kb + ((size_t)n << 14)];
    kv1[n] = kern[kb + ((size_t)n << 14) + 128];
  }
  float car0[16], car1[16];
#pragma unroll
  for (int c = 0; c < 16; ++c) { car0[c] = 0.f; car1[c] = 0.f; }
#pragma unroll
  for (int n = 0; n < 25; ++n) {
    int ki = n / 5, kj = n - ki * 5;
    int p0 = (y0 + ki) * 20 + lx + kj;
    float f0[16], f1[16];
    cvt8_(*(lds_u16x8*)(&xc[p0 * 16]), &f0[0]);
    cvt8_(*(lds_u16x8*)(&xc[p0 * 16 + 8]), &f0[8]);
    cvt8_(*(lds_u16x8*)(&xc[(p0 + 20) * 16]), &f1[0]);
    cvt8_(*(lds_u16x8*)(&xc[(p0 + 20) * 16 + 8]), &f1[8]);
#pragma unroll
    for (int c = 0; c < 16; ++c) {
      car0[c] = fmaf(f0[c], kv0[n], car0[c]);
      car1[c] = fmaf(f1[c], kv1[n], car1[c]);
    }
  }
#pragma unroll
  for (int c = 0; c < 16; ++c) {
    size_t ob = (((size_t)(b * 256 + ocg * 16 + c)) << 14) + gy0 * 128 + gx;
    float st0 = out[ob], st1 = out[ob + 128];
    out[ob] = fmaf(gv, car0[c] - st0, st0);
    out[ob + 128] = fmaf(gv, car1[c] - st1, st1);
  }
}

// ---------------------------------------------------------------- launcher
extern "C" void kernel_launch(void* const* d_in, const int* in_sizes, int n_in,
                              void* d_out, int out_size, void* d_ws, size_t ws_size,
                              hipStream_t stream) {
  const float* x      = (const float*)d_in[0];
  const float* ke_w1  = (const float*)d_in[1];
  const float* ke_b1  = (const float*)d_in[2];
  const float* ke_bng = (const float*)d_in[3];
  const float* ke_bnb = (const float*)d_in[4];
  const float* ke_bnm = (const float*)d_in[5];
  const float* ke_bnv = (const float*)d_in[6];
  const float* ke_w2  = (const float*)d_in[7];
  const float* ke_b2  = (const float*)d_in[8];
  const float* bs_w   = (const float*)d_in[9];
  const float* bs_b   = (const float*)d_in[10];
  const float* bs_bng = (const float*)d_in[11];
  const float* bs_bnb = (const float*)d_in[12];
  const float* bs_bnm = (const float*)d_in[13];
  const float* bs_bnv = (const float*)d_in[14];
  const float* g_w    = (const float*)d_in[15];
  const float* g_b    = (const float*)d_in[16];
  float* outp = (float*)d_out;

  char* ws = (char*)d_ws;
  float* kern        = (float*)(ws);                      // 13,107,200 B
  float* partial     = (float*)(ws + 13107200);           // 8,192 B
  float* gout        = (float*)(ws + 13115392);           // gout uses bytes 0-31 of 256B slot
  float* zbuff       = (float*)(ws + 13115392 + 128);     // 64B zero pad (bytes 128-191)
  unsigned short* wT = (unsigned short*)(ws + 13115648);  // 1,179,648 B
  unsigned short* xT = (unsigned short*)(ws + 14295296);  // 67,108,864 B -> total 81,404,160

  // pacc (52,428,800 B) + kernelgen weight prep (~103 KB) alias d_out: all dead before
  // conv_mfma overwrites every element of out.
  float* pacc = (float*)d_out;
  float* w1f  = (float*)((char*)d_out + 52428800);  // 73,728 B
  float* b1f  = (float*)((char*)d_out + 52502528);  //  1,024 B
  float* w2t  = (float*)((char*)d_out + 52503552);  // 28,672 B

  hipMemsetAsync(partial, 0, 2048 * sizeof(float), stream);  // GAP accumulators
  kprep_kernel<<<72, 256, 0, stream>>>(ke_w1, ke_b1, ke_bng, ke_bnb, ke_bnm, ke_bnv, ke_w2,
                                       w1f, b1f, w2t, zbuff);
  wtrans_kernel<<<2304, 256, 0, stream>>>(bs_w, wT);
  transpose_kernel<<<2048, 256, 0, stream>>>(x, xT, partial);
  gate_kernel<<<8, 256, 0, stream>>>(partial, g_w, g_b, gout);
  kernelgen_kernel<<<2048, 256, 0, stream>>>(xT, w1f, b1f, w2t, pacc);
  kcombine_kernel<<<512, 256, 0, stream>>>(pacc, ke_b2, kern);
  conv_mfma_kernel<<<2048, 256, 0, stream>>>(xT, wT, bs_b, bs_bng, bs_bnb, bs_bnm, bs_bnv,
                                             (const unsigned short*)zbuff, outp);
  carafe_blend_kernel<<<4096, 256, 0, stream>>>(xT, kern, gout, outp);
}

// Round 7
// 720.935 us; speedup vs baseline: 1.6525x; 1.6525x over previous
//
#include <hip/hip_runtime.h>

#define EPS_ 1e-5f

typedef __attribute__((ext_vector_type(8))) short bf16x8;
typedef __attribute__((ext_vector_type(8))) unsigned short u16x8;
typedef __attribute__((ext_vector_type(4))) float f32x4;
typedef __attribute__((address_space(3))) u16x8 lds_u16x8;
typedef __attribute__((address_space(3))) f32x4 lds_f32x4;

__device__ __forceinline__ float sigmoidf_(float v) { return 1.f / (1.f + __expf(-v)); }

__device__ __forceinline__ unsigned short f2bf(float f) {
  unsigned int u = __float_as_uint(f);
  u += 0x7fff + ((u >> 16) & 1);  // RNE
  return (unsigned short)(u >> 16);
}

__device__ __forceinline__ void cvt8_(u16x8 v, float* f) {
  union { u16x8 s; unsigned int u[4]; } uu;
  uu.s = v;
#pragma unroll
  for (int j = 0; j < 4; ++j) {
    f[2 * j] = __uint_as_float(uu.u[j] << 16);
    f[2 * j + 1] = __uint_as_float(uu.u[j] & 0xffff0000u);
  }
}

// async global->LDS, 16B per lane; LDS dest is wave-uniform base + lane*16
__device__ __forceinline__ void gload16(const void* g, void* l) {
  __builtin_amdgcn_global_load_lds((const __attribute__((address_space(1))) unsigned int*)(g),
                                   (__attribute__((address_space(3))) unsigned int*)(l), 16, 0, 0);
}

// ---------------------------------------------------------------- gate stage 2
__global__ void gate_kernel(const float* __restrict__ partial, const float* __restrict__ gw,
                            const float* __restrict__ gb, float* __restrict__ gout) {
  int b = blockIdx.x, t = threadIdx.x;
  float s = partial[b * 256 + t] * gw[t];
#pragma unroll
  for (int off = 32; off; off >>= 1) s += __shfl_down(s, off, 64);
  __shared__ float red[4];
  if ((t & 63) == 0) red[t >> 6] = s;
  __syncthreads();
  if (t == 0) {
    float tot = (red[0] + red[1]) + (red[2] + red[3]);
    gout[b] = sigmoidf_(tot * (1.f / 16384.f) + gb[0]);
  }
}

// ---------------------------------------------------------------- weight transform (dense conv)
__global__ void wtrans_kernel(const float* __restrict__ w, unsigned short* __restrict__ wT) {
  int n = blockIdx.x * 256 + threadIdx.x;  // 589824
  int c = n & 31, oc = (n >> 5) & 255, t9 = n >> 13;
  int cb = t9 / 9, tap = t9 - cb * 9;
  wT[n] = f2bf(w[(oc * 256 + cb * 32 + c) * 9 + tap]);
}

// ---------------------------------------------------------------- kernelgen weight prep
// w1f: [g=32][tp=9][o=8][ic=8] fp32, BN-scale folded in.
// b1f: [c=256] BN-folded bias.  w2t: [c=256][28] (n<25 valid) transposed 1x1 weights.
// zb: 16 floats (64B) of zeros — halo source for conv_mfma's global_load_lds.
__global__ void kprep_kernel(const float* __restrict__ w1, const float* __restrict__ b1,
                             const float* __restrict__ bng, const float* __restrict__ bnb,
                             const float* __restrict__ bnm, const float* __restrict__ bnv,
                             const float* __restrict__ w2, float* __restrict__ w1f,
                             float* __restrict__ b1f, float* __restrict__ w2t,
                             float* __restrict__ zb) {
  int n = blockIdx.x * 256 + threadIdx.x;  // 72 blocks -> 18432 threads
  if (n < 16) zb[n] = 0.f;
  if (n < 256) {
    float s = bng[n] * rsqrtf(bnv[n] + EPS_);
    b1f[n] = (b1[n] - bnm[n]) * s + bnb[n];
  }
  if (n < 18432) {
    int ic = n & 7, o = (n >> 3) & 7, tp = (n >> 6) % 9, g = n / 576;
    int c = g * 8 + o;
    float s = bng[c] * rsqrtf(bnv[c] + EPS_);
    w1f[n] = w1[c * 72 + ic * 9 + tp] * s;
  }
  if (n < 7168) {
    int nn = n % 28, c = n / 28;
    w2t[n] = (nn < 25) ? w2[nn * 256 + c] : 0.f;
  }
}

// ---------------------------------------------------------------- x fp32 NCHW -> xT bf16 NHWC
// + fused GAP partial sums (atomicAdd into partial[b*256+ch]; saves a full x re-read).
// grid: 256 px-tiles(64) x 8 b = 2048 blocks
__global__ __launch_bounds__(256) void transpose_kernel(const float* __restrict__ x,
                                                        unsigned short* __restrict__ xT,
                                                        float* __restrict__ partial) {
  int blk = blockIdx.x;
  int tile = blk & 255, b = blk >> 8;
  int px0 = tile * 64;
  __shared__ unsigned int tr[64 * 130];  // [px][128 ch-pair words + 2 pad]
  for (int i = threadIdx.x; i < 1024; i += 256) {
    int ch2 = i >> 3, pc = i & 7;
    const float* p0 = x + (((size_t)b * 256 + ch2 * 2) << 14) + px0 + pc * 8;
    const float4* a4 = (const float4*)p0;
    const float4* b4 = (const float4*)(p0 + 16384);
    float4 a0 = a4[0], a1 = a4[1], b0 = b4[0], b1 = b4[1];
    float fa[8] = {a0.x, a0.y, a0.z, a0.w, a1.x, a1.y, a1.z, a1.w};
    float fb[8] = {b0.x, b0.y, b0.z, b0.w, b1.x, b1.y, b1.z, b1.w};
    float sa = 0.f, sb = 0.f;
#pragma unroll
    for (int j = 0; j < 8; ++j) {
      sa += fa[j];
      sb += fb[j];
      unsigned int w = (unsigned int)f2bf(fa[j]) | ((unsigned int)f2bf(fb[j]) << 16);
      tr[(pc * 8 + j) * 130 + ch2] = w;
    }
    // 8-lane group reduce (lanes pc=0..7 share ch2), then one atomic per channel
    sa += __shfl_down(sa, 4, 8); sa += __shfl_down(sa, 2, 8); sa += __shfl_down(sa, 1, 8);
    sb += __shfl_down(sb, 4, 8); sb += __shfl_down(sb, 2, 8); sb += __shfl_down(sb, 1, 8);
    if ((threadIdx.x & 7) == 0) {
      atomicAdd(&partial[(b << 8) + ch2 * 2], sa);
      atomicAdd(&partial[(b << 8) + ch2 * 2 + 1], sb);
    }
  }
  __syncthreads();
  for (int i = threadIdx.x; i < 2048; i += 256) {
    int px = i >> 5, kc = i & 31;
    uint4 v = *(uint4*)&tr[px * 130 + kc * 4];
    *(uint4*)(xT + ((((size_t)b << 14)) + px0 + px) * 256 + kc * 8) = v;
  }
}

// ------------------- fused: grouped conv (BN pre-folded) + SiLU + 1x1 -> partial acc
// grid: 64 tiles(16x16) x 8 b x 4 splits = 2048 blocks; each block does 2 of 8 ch rounds.
__global__ __launch_bounds__(256, 6) void kernelgen_kernel(
    const unsigned short* __restrict__ xT, const float* __restrict__ w1f,
    const float* __restrict__ b1f, const float* __restrict__ w2t, float* __restrict__ pacc) {
  int blk = blockIdx.x;
  int split = blk >> 9;
  int low = blk & 511;
  int t = low & 63, b = low >> 6;
  int px0 = (t & 7) * 16, py0 = (t >> 3) * 16;
  int lx = threadIdx.x & 15, ly = threadIdx.x >> 4;
  __shared__ unsigned short xs[324 * 40];  // [18x18 px][32 ch + 8 pad]
  float acc[25];
#pragma unroll
  for (int n = 0; n < 25; ++n) acc[n] = 0.f;

#pragma unroll 1
  for (int gi = 0; gi < 2; ++gi) {  // 2 rounds of 4 groups (32 ch) each
    int gq = split * 2 + gi;
    __syncthreads();
    for (int i = threadIdx.x; i < 1296; i += 256) {
      int s = i & 3, p = i >> 2;
      int yy = py0 + p / 18 - 1, xx = px0 + (p % 18) - 1;
      u16x8 v = (u16x8)(unsigned short)0;
      if (((unsigned)yy < 128u) && ((unsigned)xx < 128u))
        v = *(const u16x8*)(xT + (((size_t)(b << 14)) + yy * 128 + xx) * 256 + gq * 32 + s * 8);
      *(lds_u16x8*)(&xs[p * 40 + s * 8]) = v;
    }
    __syncthreads();
#pragma unroll
    for (int s = 0; s < 4; ++s) {
      int g = gq * 4 + s;
      const float* wg = w1f + g * 576;  // [tp][o][ic], wave-uniform -> s_load
      const float* bp = b1f + g * 8;
      float h[8];
#pragma unroll
      for (int o = 0; o < 8; ++o) h[o] = bp[o];
#pragma unroll
      for (int tp = 0; tp < 9; ++tp) {
        float xv[8];
        u16x8 v = *(lds_u16x8*)(&xs[((ly + tp / 3) * 18 + lx + tp % 3) * 40 + s * 8]);
        cvt8_(v, xv);
        const float* wt = wg + tp * 64;
#pragma unroll
        for (int o = 0; o < 8; ++o)
#pragma unroll
          for (int ic = 0; ic < 8; ++ic) h[o] = fmaf(xv[ic], wt[o * 8 + ic], h[o]);
      }
#pragma unroll
      for (int o = 0; o < 8; ++o) {
        float sv = h[o] * sigmoidf_(h[o]);
        const float* w2p = w2t + (g * 8 + o) * 28;  // 25 contiguous floats
#pragma unroll
        for (int n = 0; n < 25; ++n) acc[n] = fmaf(sv, w2p[n], acc[n]);
      }
    }
  }
  size_t base = (((size_t)(b * 4 + split) * 25) << 14) + (py0 + ly) * 128 + px0 + lx;
#pragma unroll
  for (int n = 0; n < 25; ++n) pacc[base + ((size_t)n << 14)] = acc[n];
}

// ---------------------------------------------------------------- combine splits + softmax
__global__ __launch_bounds__(256) void kcombine_kernel(const float* __restrict__ pacc,
                                                       const float* __restrict__ b2,
                                                       float* __restrict__ kern) {
  int pix = blockIdx.x * 256 + threadIdx.x;  // 131072
  int b = pix >> 14, p = pix & 16383;
  float a[25];
#pragma unroll
  for (int n = 0; n < 25; ++n) a[n] = b2[n];
#pragma unroll
  for (int s = 0; s < 4; ++s) {
    const float* pp = pacc + (((size_t)(b * 4 + s) * 25) << 14) + p;
#pragma unroll
    for (int n = 0; n < 25; ++n) a[n] += pp[(size_t)n << 14];
  }
  float m = a[0];
#pragma unroll
  for (int n = 1; n < 25; ++n) m = fmaxf(m, a[n]);
  float sum = 0.f;
#pragma unroll
  for (int n = 0; n < 25; ++n) { a[n] = __expf(a[n] - m); sum += a[n]; }
  float inv = 1.f / sum;
  size_t base = (((size_t)b * 25) << 14) + p;
#pragma unroll
  for (int n = 0; n < 25; ++n) kern[base + ((size_t)n << 14)] = a[n] * inv;
}

// ---------------------------------------------------------------- dense conv via MFMA
// M=128 px (one row) x N=128 oc; K = 24 rows (8 cb x 3 kh) x 32 ch.
// ROW-PAIR RING-4 PIPELINE: rows processed in pairs (12 phases); ring of 4 row slots
// (33,280B LDS). Per pair P: [vmcnt(6): rows 2P,2P+1 landed, stages for 2P+2,2P+3 in
// flight] [barrier] [2 rows x 48 MFMA + 24 bfrag loads, setprio(1)] [barrier]
// [stage rows 2P+4,2P+5 into the slots just freed]. Halves barrier count vs per-row
// phases and amortizes the wT bfrag L2 head-latency over ~1860 cyc of MFMA.
// launch_bounds(256,4): acc[4][4] needs 64 AGPR + ~60 VGPR = 124 <= 128 budget
// (256,6 spilled acc to scratch: R6 regression, VGPR=40, 1.9GB scratch traffic).
// Swizzle s = k ^ ((px>>1)&3) on the source; linear DMA dest; swizzled read.
// bid XCD-swizzle: each XCD gets 256 consecutive logical blocks (one batch image).
__global__ __launch_bounds__(256, 4) void conv_mfma_kernel(
    const unsigned short* __restrict__ xT, const unsigned short* __restrict__ wT,
    const float* __restrict__ bb, const float* __restrict__ bng, const float* __restrict__ bnb,
    const float* __restrict__ bnm, const float* __restrict__ bnv,
    const unsigned short* __restrict__ zbuf, float* __restrict__ out) {
  int nb = ((blockIdx.x & 7) << 8) | (blockIdx.x >> 3);  // XCD swizzle (2048 % 8 == 0)
  int ocb = nb & 1, y = (nb >> 1) & 127, b = nb >> 8;
  int tid = threadIdx.x, lane = tid & 63, wid = tid >> 6;
  int wy = wid >> 1, wx = wid & 1;
  int m_l = lane & 15, kgrp = lane >> 4;

  __shared__ char smem[33280];  // ring: 4 x 8320B row slots; epilogue sbuf 32x132x4=16896B
  unsigned short* xs = (unsigned short*)smem;
  float* sbuf = (float*)smem;
  const char* zc = (const char*)zbuf;

  // per-thread staging constants: wave w covers granules [w*130, w*130+130)
  int g0 = wid * 130 + lane, g1 = g0 + 64, g2 = wid * 130 + 128 + lane;  // g2: lane<2
  int px0_ = g0 >> 2, k0_ = g0 & 3, s0_ = k0_ ^ ((px0_ >> 1) & 3), gx0 = px0_ - 1;
  int px1_ = g1 >> 2, k1_ = g1 & 3, s1_ = k1_ ^ ((px1_ >> 1) & 3), gx1 = px1_ - 1;
  int px2_ = g2 >> 2, k2_ = g2 & 3, s2_ = k2_ ^ ((px2_ >> 1) & 3), gx2 = px2_ - 1;
  bool ok0 = (unsigned)gx0 < 128u, ok1 = (unsigned)gx1 < 128u, ok2 = (unsigned)gx2 < 128u;
  int off0 = gx0 * 512 + s0_ * 16, off1 = gx1 * 512 + s1_ * 16, off2 = gx2 * 512 + s2_ * 16;
  int d0 = (wid * 130) * 16, d1 = d0 + 1024, d2 = d0 + 2048;  // wave-uniform LDS bases

#define STAGE_ROW(slotB_, cbn_, khn_)                                                       \
  do {                                                                                      \
    int gy_ = y + (khn_)-1;                                                                 \
    bool gyok_ = ((unsigned)gy_ < 128u);                                                    \
    const char* rb_ =                                                                       \
        (const char*)xT + (((size_t)b << 14) + (size_t)(gy_ & 127) * 128) * 512 + (cbn_)*64;\
    gload16((gyok_ && ok0) ? rb_ + off0 : zc, smem + (slotB_) + d0);                        \
    gload16((gyok_ && ok1) ? rb_ + off1 : zc, smem + (slotB_) + d1);                        \
    if (lane < 2) gload16((gyok_ && ok2) ? rb_ + off2 : zc, smem + (slotB_) + d2);          \
  } while (0)

  f32x4 acc[4][4];
#pragma unroll
  for (int mt = 0; mt < 4; ++mt)
#pragma unroll
    for (int nt = 0; nt < 4; ++nt) acc[mt][nt] = (f32x4)0.f;

  // prologue: stage rows 0..3 (row r -> cb=r/3, kh=r%3, slot r&3)
  STAGE_ROW(0, 0, 0);
  STAGE_ROW(8320, 0, 1);
  STAGE_ROW(16640, 0, 2);
  STAGE_ROW(24960, 1, 0);

  // per-thread bfrag base offset (ushorts); row R tap kw lives at +(R*3+kw)*8192
  const unsigned short* wTb = wT + ((size_t)(ocb * 128 + wx * 64 + m_l) * 32 + kgrp * 8);
  int wybase = wy * 64;
  int khn = 1, cbn = 1;  // next row to stage = 4 -> cb1,kh1

#pragma unroll 1
  for (int P = 0; P < 12; ++P) {
    if (P < 11) {
      asm volatile("s_waitcnt vmcnt(6)" ::: "memory");  // rows 2P,2P+1 landed
    } else {
      asm volatile("s_waitcnt vmcnt(0)" ::: "memory");
    }
    __builtin_amdgcn_s_barrier();
    asm volatile("" ::: "memory");
    __builtin_amdgcn_s_setprio(1);
#pragma unroll
    for (int half = 0; half < 2; ++half) {
      int R = 2 * P + half;
      const unsigned short* xb = xs + (R & 3) * 4160;
#pragma unroll
      for (int kw = 0; kw < 3; ++kw) {
        bf16x8 bfrag[4];
        const unsigned short* wb = wTb + (size_t)(R * 3 + kw) * 8192;
#pragma unroll
        for (int nt = 0; nt < 4; ++nt) bfrag[nt] = *(const bf16x8*)(wb + nt * 512);
#pragma unroll
        for (int mt = 0; mt < 4; ++mt) {
          int apx = wybase + mt * 16 + m_l + kw;
          int kk = kgrp ^ ((apx >> 1) & 3);
          bf16x8 af =
              *(__attribute__((address_space(3))) bf16x8*)(&xb[apx * 32 + kk * 8]);
#pragma unroll
          for (int nt = 0; nt < 4; ++nt)
            acc[mt][nt] =
                __builtin_amdgcn_mfma_f32_16x16x32_bf16(af, bfrag[nt], acc[mt][nt], 0, 0, 0);
        }
      }
    }
    __builtin_amdgcn_s_setprio(0);
    __builtin_amdgcn_s_barrier();  // slots (2P)&3, (2P+1)&3 free
    asm volatile("" ::: "memory");
    if (P < 10) {
      // stage rows 2P+4 and 2P+5 into the just-freed slots
      STAGE_ROW((size_t)((2 * P + 4) & 3) * 8320, cbn, khn);
      ++khn;
      if (khn == 3) { khn = 0; ++cbn; }
      STAGE_ROW((size_t)((2 * P + 5) & 3) * 8320, cbn, khn);
      ++khn;
      if (khn == 3) { khn = 0; ++cbn; }
    }
  }
#undef STAGE_ROW

  float scale4[4], bias4[4];
#pragma unroll
  for (int nt = 0; nt < 4; ++nt) {
    int oc = ocb * 128 + wx * 64 + nt * 16 + m_l;
    float s = bng[oc] * rsqrtf(bnv[oc] + EPS_);
    scale4[nt] = s;
    bias4[nt] = bnb[oc] + (bb[oc] - bnm[oc]) * s;
  }

  // epilogue: 4 passes of 32 oc through a 16,896B LDS transpose buffer
#pragma unroll
  for (int q = 0; q < 4; ++q) {
    __syncthreads();
    if (wx == (q >> 1)) {
#pragma unroll
      for (int half = 0; half < 2; ++half) {
        int nt = (q & 1) * 2 + half;
#pragma unroll
        for (int mt = 0; mt < 4; ++mt) {
          f32x4 v = acc[mt][nt];
          float o4[4];
#pragma unroll
          for (int r = 0; r < 4; ++r) {
            float hv = v[r] * scale4[nt] + bias4[nt];
            o4[r] = hv * sigmoidf_(hv);
          }
          int px = wybase + mt * 16 + kgrp * 4;
          *(lds_f32x4*)(&sbuf[(half * 16 + m_l) * 132 + px]) = (f32x4){o4[0], o4[1], o4[2], o4[3]};
        }
      }
    }
    __syncthreads();
    int kc = tid & 31, oc0 = tid >> 5;
#pragma unroll
    for (int i = 0; i < 4; ++i) {
      int ocl = oc0 + i * 8;
      f32x4 v = *(lds_f32x4*)(&sbuf[ocl * 132 + kc * 4]);
      *(f32x4*)(out + (((size_t)(b * 256 + ocb * 128 + q * 32 + ocl)) << 14) + y * 128 + kc * 4) =
          v;
    }
  }
}

// ---------------------------------------------------------------- CARAFE + blend (RMW on out)
// grid: 16 ch-groups x 8 bx x 4 by x 8 b = 4096 blocks; tile 16ch x 32y x 16x
__global__ __launch_bounds__(256) void carafe_blend_kernel(
    const unsigned short* __restrict__ xT, const float* __restrict__ kern,
    const float* __restrict__ gq, float* __restrict__ out) {
  int blk = blockIdx.x;
  int ocg = blk & 15, bx = (blk >> 4) & 7, by = (blk >> 7) & 3, b = blk >> 9;
  __shared__ unsigned short xc[720 * 16];  // [36x20 px][16 ch]
  for (int i = threadIdx.x; i < 1440; i += 256) {
    int half = i & 1, p = i >> 1;
    int py = p / 20, pxx = p - py * 20;
    int yy = by * 32 + py - 2, xx = bx * 16 + pxx - 2;
    yy = yy < 0 ? -yy : (yy > 127 ? 254 - yy : yy);
    xx = xx < 0 ? -xx : (xx > 127 ? 254 - xx : xx);
    *(lds_u16x8*)(&xc[p * 16 + half * 8]) =
        *(const u16x8*)(xT + (((size_t)(b << 14)) + yy * 128 + xx) * 256 + ocg * 16 + half * 8);
  }
  __syncthreads();
  int lx = threadIdx.x & 15, y0 = (threadIdx.x >> 4) * 2;
  float gv = gq[b];
  int gy0 = by * 32 + y0, gx = bx * 16 + lx;
  float kv0[25], kv1[25];
  size_t kb = (((size_t)b * 25) << 14) + gy0 * 128 + gx;
#pragma unroll
  for (int n = 0; n < 25; ++n) {
    kv0[n] = kern[kb + ((size_t)n << 14)];
    kv1[n] = kern[kb + ((size_t)n << 14) + 128];
  }
  float car0[16], car1[16];
#pragma unroll
  for (int c = 0; c < 16; ++c) { car0[c] = 0.f; car1[c] = 0.f; }
#pragma unroll
  for (int n = 0; n < 25; ++n) {
    int ki = n / 5, kj = n - ki * 5;
    int p0 = (y0 + ki) * 20 + lx + kj;
    float f0[16], f1[16];
    cvt8_(*(lds_u16x8*)(&xc[p0 * 16]), &f0[0]);
    cvt8_(*(lds_u16x8*)(&xc[p0 * 16 + 8]), &f0[8]);
    cvt8_(*(lds_u16x8*)(&xc[(p0 + 20) * 16]), &f1[0]);
    cvt8_(*(lds_u16x8*)(&xc[(p0 + 20) * 16 + 8]), &f1[8]);
#pragma unroll
    for (int c = 0; c < 16; ++c) {
      car0[c] = fmaf(f0[c], kv0[n], car0[c]);
      car1[c] = fmaf(f1[c], kv1[n], car1[c]);
    }
  }
#pragma unroll
  for (int c = 0; c < 16; ++c) {
    size_t ob = (((size_t)(b * 256 + ocg * 16 + c)) << 14) + gy0 * 128 + gx;
    float st0 = out[ob], st1 = out[ob + 128];
    out[ob] = fmaf(gv, car0[c] - st0, st0);
    out[ob + 128] = fmaf(gv, car1[c] - st1, st1);
  }
}

// ---------------------------------------------------------------- launcher
extern "C" void kernel_launch(void* const* d_in, const int* in_sizes, int n_in,
                              void* d_out, int out_size, void* d_ws, size_t ws_size,
                              hipStream_t stream) {
  const float* x      = (const float*)d_in[0];
  const float* ke_w1  = (const float*)d_in[1];
  const float* ke_b1  = (const float*)d_in[2];
  const float* ke_bng = (const float*)d_in[3];
  const float* ke_bnb = (const float*)d_in[4];
  const float* ke_bnm = (const float*)d_in[5];
  const float* ke_bnv = (const float*)d_in[6];
  const float* ke_w2  = (const float*)d_in[7];
  const float* ke_b2  = (const float*)d_in[8];
  const float* bs_w   = (const float*)d_in[9];
  const float* bs_b   = (const float*)d_in[10];
  const float* bs_bng = (const float*)d_in[11];
  const float* bs_bnb = (const float*)d_in[12];
  const float* bs_bnm = (const float*)d_in[13];
  const float* bs_bnv = (const float*)d_in[14];
  const float* g_w    = (const float*)d_in[15];
  const float* g_b    = (const float*)d_in[16];
  float* outp = (float*)d_out;

  char* ws = (char*)d_ws;
  float* kern        = (float*)(ws);                      // 13,107,200 B
  float* partial     = (float*)(ws + 13107200);           // 8,192 B
  float* gout        = (float*)(ws + 13115392);           // gout uses bytes 0-31 of 256B slot
  float* zbuff       = (float*)(ws + 13115392 + 128);     // 64B zero pad (bytes 128-191)
  unsigned short* wT = (unsigned short*)(ws + 13115648);  // 1,179,648 B
  unsigned short* xT = (unsigned short*)(ws + 14295296);  // 67,108,864 B -> total 81,404,160

  // pacc (52,428,800 B) + kernelgen weight prep (~103 KB) alias d_out: all dead before
  // conv_mfma overwrites every element of out.
  float* pacc = (float*)d_out;
  float* w1f  = (float*)((char*)d_out + 52428800);  // 73,728 B
  float* b1f  = (float*)((char*)d_out + 52502528);  //  1,024 B
  float* w2t  = (float*)((char*)d_out + 52503552);  // 28,672 B

  hipMemsetAsync(partial, 0, 2048 * sizeof(float), stream);  // GAP accumulators
  kprep_kernel<<<72, 256, 0, stream>>>(ke_w1, ke_b1, ke_bng, ke_bnb, ke_bnm, ke_bnv, ke_w2,
                                       w1f, b1f, w2t, zbuff);
  wtrans_kernel<<<2304, 256, 0, stream>>>(bs_w, wT);
  transpose_kernel<<<2048, 256, 0, stream>>>(x, xT, partial);
  gate_kernel<<<8, 256, 0, stream>>>(partial, g_w, g_b, gout);
  kernelgen_kernel<<<2048, 256, 0, stream>>>(xT, w1f, b1f, w2t, pacc);
  kcombine_kernel<<<512, 256, 0, stream>>>(pacc, ke_b2, kern);
  conv_mfma_kernel<<<2048, 256, 0, stream>>>(xT, wT, bs_b, bs_bng, bs_bnb, bs_bnm, bs_bnv,
                                             (const unsigned short*)zbuff, outp);
  carafe_blend_kernel<<<4096, 256, 0, stream>>>(xT, kern, gout, outp);
}

// Round 8
// 691.113 us; speedup vs baseline: 1.7238x; 1.0431x over previous
//
#include <hip/hip_runtime.h>

#define EPS_ 1e-5f

typedef __attribute__((ext_vector_type(8))) short bf16x8;
typedef __attribute__((ext_vector_type(8))) unsigned short u16x8;
typedef __attribute__((ext_vector_type(4))) float f32x4;
typedef __attribute__((address_space(3))) u16x8 lds_u16x8;
typedef __attribute__((address_space(3))) f32x4 lds_f32x4;

__device__ __forceinline__ float sigmoidf_(float v) { return 1.f / (1.f + __expf(-v)); }

__device__ __forceinline__ unsigned short f2bf(float f) {
  unsigned int u = __float_as_uint(f);
  u += 0x7fff + ((u >> 16) & 1);  // RNE
  return (unsigned short)(u >> 16);
}

__device__ __forceinline__ void cvt8_(u16x8 v, float* f) {
  union { u16x8 s; unsigned int u[4]; } uu;
  uu.s = v;
#pragma unroll
  for (int j = 0; j < 4; ++j) {
    f[2 * j] = __uint_as_float(uu.u[j] << 16);
    f[2 * j + 1] = __uint_as_float(uu.u[j] & 0xffff0000u);
  }
}

// async global->LDS, 16B per lane; LDS dest is wave-uniform base + lane*16
__device__ __forceinline__ void gload16(const void* g, void* l) {
  __builtin_amdgcn_global_load_lds((const __attribute__((address_space(1))) unsigned int*)(g),
                                   (__attribute__((address_space(3))) unsigned int*)(l), 16, 0, 0);
}

// ---------------------------------------------------------------- gate stage 2
__global__ void gate_kernel(const float* __restrict__ partial, const float* __restrict__ gw,
                            const float* __restrict__ gb, float* __restrict__ gout) {
  int b = blockIdx.x, t = threadIdx.x;
  float s = partial[b * 256 + t] * gw[t];
#pragma unroll
  for (int off = 32; off; off >>= 1) s += __shfl_down(s, off, 64);
  __shared__ float red[4];
  if ((t & 63) == 0) red[t >> 6] = s;
  __syncthreads();
  if (t == 0) {
    float tot = (red[0] + red[1]) + (red[2] + red[3]);
    gout[b] = sigmoidf_(tot * (1.f / 16384.f) + gb[0]);
  }
}

// ---------------------------------------------------------------- weight transform (dense conv)
__global__ void wtrans_kernel(const float* __restrict__ w, unsigned short* __restrict__ wT) {
  int n = blockIdx.x * 256 + threadIdx.x;  // 589824
  int c = n & 31, oc = (n >> 5) & 255, t9 = n >> 13;
  int cb = t9 / 9, tap = t9 - cb * 9;
  wT[n] = f2bf(w[(oc * 256 + cb * 32 + c) * 9 + tap]);
}

// ---------------------------------------------------------------- kernelgen weight prep
// w1f: [g=32][tp=9][o=8][ic=8] fp32, BN-scale folded in.
// b1f: [c=256] BN-folded bias.  w2t: [c=256][28] (n<25 valid) transposed 1x1 weights.
// zb: 16 floats (64B) of zeros — halo source for conv_mfma's global_load_lds.
__global__ void kprep_kernel(const float* __restrict__ w1, const float* __restrict__ b1,
                             const float* __restrict__ bng, const float* __restrict__ bnb,
                             const float* __restrict__ bnm, const float* __restrict__ bnv,
                             const float* __restrict__ w2, float* __restrict__ w1f,
                             float* __restrict__ b1f, float* __restrict__ w2t,
                             float* __restrict__ zb) {
  int n = blockIdx.x * 256 + threadIdx.x;  // 72 blocks -> 18432 threads
  if (n < 16) zb[n] = 0.f;
  if (n < 256) {
    float s = bng[n] * rsqrtf(bnv[n] + EPS_);
    b1f[n] = (b1[n] - bnm[n]) * s + bnb[n];
  }
  if (n < 18432) {
    int ic = n & 7, o = (n >> 3) & 7, tp = (n >> 6) % 9, g = n / 576;
    int c = g * 8 + o;
    float s = bng[c] * rsqrtf(bnv[c] + EPS_);
    w1f[n] = w1[c * 72 + ic * 9 + tp] * s;
  }
  if (n < 7168) {
    int nn = n % 28, c = n / 28;
    w2t[n] = (nn < 25) ? w2[nn * 256 + c] : 0.f;
  }
}

// ---------------------------------------------------------------- x fp32 NCHW -> xT bf16 NHWC
// + fused GAP partial sums (atomicAdd into partial[b*256+ch]; saves a full x re-read).
// grid: 256 px-tiles(64) x 8 b = 2048 blocks
__global__ __launch_bounds__(256) void transpose_kernel(const float* __restrict__ x,
                                                        unsigned short* __restrict__ xT,
                                                        float* __restrict__ partial) {
  int blk = blockIdx.x;
  int tile = blk & 255, b = blk >> 8;
  int px0 = tile * 64;
  __shared__ unsigned int tr[64 * 130];  // [px][128 ch-pair words + 2 pad]
  for (int i = threadIdx.x; i < 1024; i += 256) {
    int ch2 = i >> 3, pc = i & 7;
    const float* p0 = x + (((size_t)b * 256 + ch2 * 2) << 14) + px0 + pc * 8;
    const float4* a4 = (const float4*)p0;
    const float4* b4 = (const float4*)(p0 + 16384);
    float4 a0 = a4[0], a1 = a4[1], b0 = b4[0], b1 = b4[1];
    float fa[8] = {a0.x, a0.y, a0.z, a0.w, a1.x, a1.y, a1.z, a1.w};
    float fb[8] = {b0.x, b0.y, b0.z, b0.w, b1.x, b1.y, b1.z, b1.w};
    float sa = 0.f, sb = 0.f;
#pragma unroll
    for (int j = 0; j < 8; ++j) {
      sa += fa[j];
      sb += fb[j];
      unsigned int w = (unsigned int)f2bf(fa[j]) | ((unsigned int)f2bf(fb[j]) << 16);
      tr[(pc * 8 + j) * 130 + ch2] = w;
    }
    // 8-lane group reduce (lanes pc=0..7 share ch2), then one atomic per channel
    sa += __shfl_down(sa, 4, 8); sa += __shfl_down(sa, 2, 8); sa += __shfl_down(sa, 1, 8);
    sb += __shfl_down(sb, 4, 8); sb += __shfl_down(sb, 2, 8); sb += __shfl_down(sb, 1, 8);
    if ((threadIdx.x & 7) == 0) {
      atomicAdd(&partial[(b << 8) + ch2 * 2], sa);
      atomicAdd(&partial[(b << 8) + ch2 * 2 + 1], sb);
    }
  }
  __syncthreads();
  for (int i = threadIdx.x; i < 2048; i += 256) {
    int px = i >> 5, kc = i & 31;
    uint4 v = *(uint4*)&tr[px * 130 + kc * 4];
    *(uint4*)(xT + ((((size_t)b << 14)) + px0 + px) * 256 + kc * 8) = v;
  }
}

// ------------------- fused: grouped conv (BN pre-folded) + SiLU + 1x1 -> partial acc
// grid: 64 tiles(16x16) x 8 b x 4 splits = 2048 blocks; each block does 2 of 8 ch rounds.
__global__ __launch_bounds__(256, 6) void kernelgen_kernel(
    const unsigned short* __restrict__ xT, const float* __restrict__ w1f,
    const float* __restrict__ b1f, const float* __restrict__ w2t, float* __restrict__ pacc) {
  int blk = blockIdx.x;
  int split = blk >> 9;
  int low = blk & 511;
  int t = low & 63, b = low >> 6;
  int px0 = (t & 7) * 16, py0 = (t >> 3) * 16;
  int lx = threadIdx.x & 15, ly = threadIdx.x >> 4;
  __shared__ unsigned short xs[324 * 40];  // [18x18 px][32 ch + 8 pad]
  float acc[25];
#pragma unroll
  for (int n = 0; n < 25; ++n) acc[n] = 0.f;

#pragma unroll 1
  for (int gi = 0; gi < 2; ++gi) {  // 2 rounds of 4 groups (32 ch) each
    int gq = split * 2 + gi;
    __syncthreads();
    for (int i = threadIdx.x; i < 1296; i += 256) {
      int s = i & 3, p = i >> 2;
      int yy = py0 + p / 18 - 1, xx = px0 + (p % 18) - 1;
      u16x8 v = (u16x8)(unsigned short)0;
      if (((unsigned)yy < 128u) && ((unsigned)xx < 128u))
        v = *(const u16x8*)(xT + (((size_t)(b << 14)) + yy * 128 + xx) * 256 + gq * 32 + s * 8);
      *(lds_u16x8*)(&xs[p * 40 + s * 8]) = v;
    }
    __syncthreads();
#pragma unroll
    for (int s = 0; s < 4; ++s) {
      int g = gq * 4 + s;
      const float* wg = w1f + g * 576;  // [tp][o][ic], wave-uniform -> s_load
      const float* bp = b1f + g * 8;
      float h[8];
#pragma unroll
      for (int o = 0; o < 8; ++o) h[o] = bp[o];
#pragma unroll
      for (int tp = 0; tp < 9; ++tp) {
        float xv[8];
        u16x8 v = *(lds_u16x8*)(&xs[((ly + tp / 3) * 18 + lx + tp % 3) * 40 + s * 8]);
        cvt8_(v, xv);
        const float* wt = wg + tp * 64;
#pragma unroll
        for (int o = 0; o < 8; ++o)
#pragma unroll
          for (int ic = 0; ic < 8; ++ic) h[o] = fmaf(xv[ic], wt[o * 8 + ic], h[o]);
      }
#pragma unroll
      for (int o = 0; o < 8; ++o) {
        float sv = h[o] * sigmoidf_(h[o]);
        const float* w2p = w2t + (g * 8 + o) * 28;  // 25 contiguous floats
#pragma unroll
        for (int n = 0; n < 25; ++n) acc[n] = fmaf(sv, w2p[n], acc[n]);
      }
    }
  }
  size_t base = (((size_t)(b * 4 + split) * 25) << 14) + (py0 + ly) * 128 + px0 + lx;
#pragma unroll
  for (int n = 0; n < 25; ++n) pacc[base + ((size_t)n << 14)] = acc[n];
}

// ---------------------------------------------------------------- combine splits + softmax
__global__ __launch_bounds__(256) void kcombine_kernel(const float* __restrict__ pacc,
                                                       const float* __restrict__ b2,
                                                       float* __restrict__ kern) {
  int pix = blockIdx.x * 256 + threadIdx.x;  // 131072
  int b = pix >> 14, p = pix & 16383;
  float a[25];
#pragma unroll
  for (int n = 0; n < 25; ++n) a[n] = b2[n];
#pragma unroll
  for (int s = 0; s < 4; ++s) {
    const float* pp = pacc + (((size_t)(b * 4 + s) * 25) << 14) + p;
#pragma unroll
    for (int n = 0; n < 25; ++n) a[n] += pp[(size_t)n << 14];
  }
  float m = a[0];
#pragma unroll
  for (int n = 1; n < 25; ++n) m = fmaxf(m, a[n]);
  float sum = 0.f;
#pragma unroll
  for (int n = 0; n < 25; ++n) { a[n] = __expf(a[n] - m); sum += a[n]; }
  float inv = 1.f / sum;
  size_t base = (((size_t)b * 25) << 14) + p;
#pragma unroll
  for (int n = 0; n < 25; ++n) kern[base + ((size_t)n << 14)] = a[n] * inv;
}

// ---------------------------------------------------------------- dense conv via MFMA
// M=128 px (one row) x N=128 oc; K = 24 rows (8 cb x 3 kh) x 32 ch.
// WAVE = 128px x 32oc (mt=8, nt=2): each wave owns a DISTINCT 32-oc band ->
// zero wT redundancy in the block (B L2 traffic halves vs 64x64 waves), per-wave
// B loads 6/row, each bfrag feeds 8 MFMAs. Wave covers whole oc rows -> direct
// f32x4 global stores from acc (LDS-transpose epilogue + its barriers eliminated).
// ROW-PAIR RING-4 PIPELINE (unchanged): per pair P: [vmcnt(6)] [barrier]
// [2 rows x (3kw x {2 bfrag, 8x(ds_read af, 2 MFMA)})] [barrier] [stage 2 rows].
// launch_bounds(256,4): acc 64 AGPR + VGPR<=64 (R6 lesson: (256,6) spills acc).
// Swizzle s = k ^ ((px>>1)&3) on the source; linear DMA dest; swizzled read.
// bid XCD-swizzle: each XCD gets 256 consecutive logical blocks (one batch image).
__global__ __launch_bounds__(256, 4) void conv_mfma_kernel(
    const unsigned short* __restrict__ xT, const unsigned short* __restrict__ wT,
    const float* __restrict__ bb, const float* __restrict__ bng, const float* __restrict__ bnb,
    const float* __restrict__ bnm, const float* __restrict__ bnv,
    const unsigned short* __restrict__ zbuf, float* __restrict__ out) {
  int nb = ((blockIdx.x & 7) << 8) | (blockIdx.x >> 3);  // XCD swizzle (2048 % 8 == 0)
  int ocb = nb & 1, y = (nb >> 1) & 127, b = nb >> 8;
  int tid = threadIdx.x, lane = tid & 63, wid = tid >> 6;
  int m_l = lane & 15, kgrp = lane >> 4;

  __shared__ char smem[33280];  // ring: 4 x 8320B row slots (no epilogue buffer needed)
  unsigned short* xs = (unsigned short*)smem;
  const char* zc = (const char*)zbuf;

  // per-thread staging constants: wave w covers granules [w*130, w*130+130)
  int g0 = wid * 130 + lane, g1 = g0 + 64, g2 = wid * 130 + 128 + lane;  // g2: lane<2
  int px0_ = g0 >> 2, k0_ = g0 & 3, s0_ = k0_ ^ ((px0_ >> 1) & 3), gx0 = px0_ - 1;
  int px1_ = g1 >> 2, k1_ = g1 & 3, s1_ = k1_ ^ ((px1_ >> 1) & 3), gx1 = px1_ - 1;
  int px2_ = g2 >> 2, k2_ = g2 & 3, s2_ = k2_ ^ ((px2_ >> 1) & 3), gx2 = px2_ - 1;
  bool ok0 = (unsigned)gx0 < 128u, ok1 = (unsigned)gx1 < 128u, ok2 = (unsigned)gx2 < 128u;
  int off0 = gx0 * 512 + s0_ * 16, off1 = gx1 * 512 + s1_ * 16, off2 = gx2 * 512 + s2_ * 16;
  int d0 = (wid * 130) * 16, d1 = d0 + 1024, d2 = d0 + 2048;  // wave-uniform LDS bases

#define STAGE_ROW(slotB_, cbn_, khn_)                                                       \
  do {                                                                                      \
    int gy_ = y + (khn_)-1;                                                                 \
    bool gyok_ = ((unsigned)gy_ < 128u);                                                    \
    const char* rb_ =                                                                       \
        (const char*)xT + (((size_t)b << 14) + (size_t)(gy_ & 127) * 128) * 512 + (cbn_)*64;\
    gload16((gyok_ && ok0) ? rb_ + off0 : zc, smem + (slotB_) + d0);                        \
    gload16((gyok_ && ok1) ? rb_ + off1 : zc, smem + (slotB_) + d1);                        \
    if (lane < 2) gload16((gyok_ && ok2) ? rb_ + off2 : zc, smem + (slotB_) + d2);          \
  } while (0)

  f32x4 acc[8][2];
#pragma unroll
  for (int mt = 0; mt < 8; ++mt)
#pragma unroll
    for (int nt = 0; nt < 2; ++nt) acc[mt][nt] = (f32x4)0.f;

  // prologue: stage rows 0..3 (row r -> cb=r/3, kh=r%3, slot r&3)
  STAGE_ROW(0, 0, 0);
  STAGE_ROW(8320, 0, 1);
  STAGE_ROW(16640, 0, 2);
  STAGE_ROW(24960, 1, 0);

  // per-thread bfrag base (ushorts); wave owns oc band [ocb*128 + wid*32, +32)
  int oc0 = ocb * 128 + wid * 32;
  const unsigned short* wTb = wT + ((size_t)(oc0 + m_l) * 32 + kgrp * 8);
  int khn = 1, cbn = 1;  // next row to stage = 4 -> cb1,kh1

#pragma unroll 1
  for (int P = 0; P < 12; ++P) {
    if (P < 11) {
      asm volatile("s_waitcnt vmcnt(6)" ::: "memory");  // rows 2P,2P+1 landed
    } else {
      asm volatile("s_waitcnt vmcnt(0)" ::: "memory");
    }
    __builtin_amdgcn_s_barrier();
    asm volatile("" ::: "memory");
    __builtin_amdgcn_s_setprio(1);
#pragma unroll
    for (int half = 0; half < 2; ++half) {
      int R = 2 * P + half;
      const unsigned short* xb = xs + (R & 3) * 4160;
#pragma unroll
      for (int kw = 0; kw < 3; ++kw) {
        bf16x8 bfrag[2];
        const unsigned short* wb = wTb + (size_t)(R * 3 + kw) * 8192;
#pragma unroll
        for (int nt = 0; nt < 2; ++nt) bfrag[nt] = *(const bf16x8*)(wb + nt * 512);
#pragma unroll
        for (int mt = 0; mt < 8; ++mt) {
          int apx = mt * 16 + m_l + kw;
          int kk = kgrp ^ ((apx >> 1) & 3);
          bf16x8 af =
              *(__attribute__((address_space(3))) bf16x8*)(&xb[apx * 32 + kk * 8]);
#pragma unroll
          for (int nt = 0; nt < 2; ++nt)
            acc[mt][nt] =
                __builtin_amdgcn_mfma_f32_16x16x32_bf16(af, bfrag[nt], acc[mt][nt], 0, 0, 0);
        }
      }
    }
    __builtin_amdgcn_s_setprio(0);
    __builtin_amdgcn_s_barrier();  // slots (2P)&3, (2P+1)&3 free
    asm volatile("" ::: "memory");
    if (P < 10) {
      // stage rows 2P+4 and 2P+5 into the just-freed slots
      STAGE_ROW((size_t)((2 * P + 4) & 3) * 8320, cbn, khn);
      ++khn;
      if (khn == 3) { khn = 0; ++cbn; }
      STAGE_ROW((size_t)((2 * P + 5) & 3) * 8320, cbn, khn);
      ++khn;
      if (khn == 3) { khn = 0; ++cbn; }
    }
  }
#undef STAGE_ROW

  // epilogue: direct stores — wave owns oc rows [oc0, oc0+32), all 128 px.
  float scale2[2], bias2[2];
#pragma unroll
  for (int nt = 0; nt < 2; ++nt) {
    int oc = oc0 + nt * 16 + m_l;
    float s = bng[oc] * rsqrtf(bnv[oc] + EPS_);
    scale2[nt] = s;
    bias2[nt] = bnb[oc] + (bb[oc] - bnm[oc]) * s;
  }
#pragma unroll
  for (int nt = 0; nt < 2; ++nt) {
    size_t obase = (((size_t)(b * 256 + oc0 + nt * 16 + m_l)) << 14) + y * 128 + kgrp * 4;
#pragma unroll
    for (int mt = 0; mt < 8; ++mt) {
      f32x4 v = acc[mt][nt];
      float o4[4];
#pragma unroll
      for (int r = 0; r < 4; ++r) {
        float hv = v[r] * scale2[nt] + bias2[nt];
        o4[r] = hv * sigmoidf_(hv);
      }
      *(f32x4*)(out + obase + mt * 16) = (f32x4){o4[0], o4[1], o4[2], o4[3]};
    }
  }
}

// ---------------------------------------------------------------- CARAFE + blend (RMW on out)
// grid: 16 ch-groups x 8 bx x 4 by x 8 b = 4096 blocks; tile 16ch x 32y x 16x
__global__ __launch_bounds__(256) void carafe_blend_kernel(
    const unsigned short* __restrict__ xT, const float* __restrict__ kern,
    const float* __restrict__ gq, float* __restrict__ out) {
  int blk = blockIdx.x;
  int ocg = blk & 15, bx = (blk >> 4) & 7, by = (blk >> 7) & 3, b = blk >> 9;
  __shared__ unsigned short xc[720 * 16];  // [36x20 px][16 ch]
  for (int i = threadIdx.x; i < 1440; i += 256) {
    int half = i & 1, p = i >> 1;
    int py = p / 20, pxx = p - py * 20;
    int yy = by * 32 + py - 2, xx = bx * 16 + pxx - 2;
    yy = yy < 0 ? -yy : (yy > 127 ? 254 - yy : yy);
    xx = xx < 0 ? -xx : (xx > 127 ? 254 - xx : xx);
    *(lds_u16x8*)(&xc[p * 16 + half * 8]) =
        *(const u16x8*)(xT + (((size_t)(b << 14)) + yy * 128 + xx) * 256 + ocg * 16 + half * 8);
  }
  __syncthreads();
  int lx = threadIdx.x & 15, y0 = (threadIdx.x >> 4) * 2;
  float gv = gq[b];
  int gy0 = by * 32 + y0, gx = bx * 16 + lx;
  float kv0[25], kv1[25];
  size_t kb = (((size_t)b * 25) << 14) + gy0 * 128 + gx;
#pragma unroll
  for (int n = 0; n < 25; ++n) {
    kv0[n] = kern[kb + ((size_t)n << 14)];
    kv1[n] = kern[kb + ((size_t)n << 14) + 128];
  }
  float car0[16], car1[16];
#pragma unroll
  for (int c = 0; c < 16; ++c) { car0[c] = 0.f; car1[c] = 0.f; }
#pragma unroll
  for (int n = 0; n < 25; ++n) {
    int ki = n / 5, kj = n - ki * 5;
    int p0 = (y0 + ki) * 20 + lx + kj;
    float f0[16], f1[16];
    cvt8_(*(lds_u16x8*)(&xc[p0 * 16]), &f0[0]);
    cvt8_(*(lds_u16x8*)(&xc[p0 * 16 + 8]), &f0[8]);
    cvt8_(*(lds_u16x8*)(&xc[(p0 + 20) * 16]), &f1[0]);
    cvt8_(*(lds_u16x8*)(&xc[(p0 + 20) * 16 + 8]), &f1[8]);
#pragma unroll
    for (int c = 0; c < 16; ++c) {
      car0[c] = fmaf(f0[c], kv0[n], car0[c]);
      car1[c] = fmaf(f1[c], kv1[n], car1[c]);
    }
  }
#pragma unroll
  for (int c = 0; c < 16; ++c) {
    size_t ob = (((size_t)(b * 256 + ocg * 16 + c)) << 14) + gy0 * 128 + gx;
    float st0 = out[ob], st1 = out[ob + 128];
    out[ob] = fmaf(gv, car0[c] - st0, st0);
    out[ob + 128] = fmaf(gv, car1[c] - st1, st1);
  }
}

// ---------------------------------------------------------------- launcher
extern "C" void kernel_launch(void* const* d_in, const int* in_sizes, int n_in,
                              void* d_out, int out_size, void* d_ws, size_t ws_size,
                              hipStream_t stream) {
  const float* x      = (const float*)d_in[0];
  const float* ke_w1  = (const float*)d_in[1];
  const float* ke_b1  = (const float*)d_in[2];
  const float* ke_bng = (const float*)d_in[3];
  const float* ke_bnb = (const float*)d_in[4];
  const float* ke_bnm = (const float*)d_in[5];
  const float* ke_bnv = (const float*)d_in[6];
  const float* ke_w2  = (const float*)d_in[7];
  const float* ke_b2  = (const float*)d_in[8];
  const float* bs_w   = (const float*)d_in[9];
  const float* bs_b   = (const float*)d_in[10];
  const float* bs_bng = (const float*)d_in[11];
  const float* bs_bnb = (const float*)d_in[12];
  const float* bs_bnm = (const float*)d_in[13];
  const float* bs_bnv = (const float*)d_in[14];
  const float* g_w    = (const float*)d_in[15];
  const float* g_b    = (const float*)d_in[16];
  float* outp = (float*)d_out;

  char* ws = (char*)d_ws;
  float* kern        = (float*)(ws);                      // 13,107,200 B
  float* partial     = (float*)(ws + 13107200);           // 8,192 B
  float* gout        = (float*)(ws + 13115392);           // gout uses bytes 0-31 of 256B slot
  float* zbuff       = (float*)(ws + 13115392 + 128);     // 64B zero pad (bytes 128-191)
  unsigned short* wT = (unsigned short*)(ws + 13115648);  // 1,179,648 B
  unsigned short* xT = (unsigned short*)(ws + 14295296);  // 67,108,864 B -> total 81,404,160

  // pacc (52,428,800 B) + kernelgen weight prep (~103 KB) alias d_out: all dead before
  // conv_mfma overwrites every element of out.
  float* pacc = (float*)d_out;
  float* w1f  = (float*)((char*)d_out + 52428800);  // 73,728 B
  float* b1f  = (float*)((char*)d_out + 52502528);  //  1,024 B
  float* w2t  = (float*)((char*)d_out + 52503552);  // 28,672 B

  hipMemsetAsync(partial, 0, 2048 * sizeof(float), stream);  // GAP accumulators
  kprep_kernel<<<72, 256, 0, stream>>>(ke_w1, ke_b1, ke_bng, ke_bnb, ke_bnm, ke_bnv, ke_w2,
                                       w1f, b1f, w2t, zbuff);
  wtrans_kernel<<<2304, 256, 0, stream>>>(bs_w, wT);
  transpose_kernel<<<2048, 256, 0, stream>>>(x, xT, partial);
  gate_kernel<<<8, 256, 0, stream>>>(partial, g_w, g_b, gout);
  kernelgen_kernel<<<2048, 256, 0, stream>>>(xT, w1f, b1f, w2t, pacc);
  kcombine_kernel<<<512, 256, 0, stream>>>(pacc, ke_b2, kern);
  conv_mfma_kernel<<<2048, 256, 0, stream>>>(xT, wT, bs_b, bs_bng, bs_bnb, bs_bnm, bs_bnv,
                                             (const unsigned short*)zbuff, outp);
  carafe_blend_kernel<<<4096, 256, 0, stream>>>(xT, kern, gout, outp);
}

// Round 9
// 666.658 us; speedup vs baseline: 1.7870x; 1.0367x over previous
//
#include <hip/hip_runtime.h>

#define EPS_ 1e-5f

typedef __attribute__((ext_vector_type(8))) short bf16x8;
typedef __attribute__((ext_vector_type(8))) unsigned short u16x8;
typedef __attribute__((ext_vector_type(4))) float f32x4;
typedef __attribute__((address_space(3))) u16x8 lds_u16x8;
typedef __attribute__((address_space(3))) f32x4 lds_f32x4;

__device__ __forceinline__ float sigmoidf_(float v) { return 1.f / (1.f + __expf(-v)); }

__device__ __forceinline__ unsigned short f2bf(float f) {
  unsigned int u = __float_as_uint(f);
  u += 0x7fff + ((u >> 16) & 1);  // RNE
  return (unsigned short)(u >> 16);
}

__device__ __forceinline__ void cvt8_(u16x8 v, float* f) {
  union { u16x8 s; unsigned int u[4]; } uu;
  uu.s = v;
#pragma unroll
  for (int j = 0; j < 4; ++j) {
    f[2 * j] = __uint_as_float(uu.u[j] << 16);
    f[2 * j + 1] = __uint_as_float(uu.u[j] & 0xffff0000u);
  }
}

// async global->LDS, 16B per lane; LDS dest is wave-uniform base + lane*16
__device__ __forceinline__ void gload16(const void* g, void* l) {
  __builtin_amdgcn_global_load_lds((const __attribute__((address_space(1))) unsigned int*)(g),
                                   (__attribute__((address_space(3))) unsigned int*)(l), 16, 0, 0);
}

// ---------------------------------------------------------------- gate stage 2
__global__ void gate_kernel(const float* __restrict__ partial, const float* __restrict__ gw,
                            const float* __restrict__ gb, float* __restrict__ gout) {
  int b = blockIdx.x, t = threadIdx.x;
  float s = partial[b * 256 + t] * gw[t];
#pragma unroll
  for (int off = 32; off; off >>= 1) s += __shfl_down(s, off, 64);
  __shared__ float red[4];
  if ((t & 63) == 0) red[t >> 6] = s;
  __syncthreads();
  if (t == 0) {
    float tot = (red[0] + red[1]) + (red[2] + red[3]);
    gout[b] = sigmoidf_(tot * (1.f / 16384.f) + gb[0]);
  }
}

// ---------------------------------------------------------------- weight transform (dense conv)
__global__ void wtrans_kernel(const float* __restrict__ w, unsigned short* __restrict__ wT) {
  int n = blockIdx.x * 256 + threadIdx.x;  // 589824
  int c = n & 31, oc = (n >> 5) & 255, t9 = n >> 13;
  int cb = t9 / 9, tap = t9 - cb * 9;
  wT[n] = f2bf(w[(oc * 256 + cb * 32 + c) * 9 + tap]);
}

// ---------------------------------------------------------------- kernelgen weight prep
// w1f: [g=32][tp=9][o=8][ic=8] fp32, BN-scale folded in.
// b1f: [c=256] BN-folded bias.  w2t: [c=256][28] (n<25 valid) transposed 1x1 weights.
// zb: 16 floats (64B) of zeros — halo source for conv's global_load_lds.
__global__ void kprep_kernel(const float* __restrict__ w1, const float* __restrict__ b1,
                             const float* __restrict__ bng, const float* __restrict__ bnb,
                             const float* __restrict__ bnm, const float* __restrict__ bnv,
                             const float* __restrict__ w2, float* __restrict__ w1f,
                             float* __restrict__ b1f, float* __restrict__ w2t,
                             float* __restrict__ zb) {
  int n = blockIdx.x * 256 + threadIdx.x;  // 72 blocks -> 18432 threads
  if (n < 16) zb[n] = 0.f;
  if (n < 256) {
    float s = bng[n] * rsqrtf(bnv[n] + EPS_);
    b1f[n] = (b1[n] - bnm[n]) * s + bnb[n];
  }
  if (n < 18432) {
    int ic = n & 7, o = (n >> 3) & 7, tp = (n >> 6) % 9, g = n / 576;
    int c = g * 8 + o;
    float s = bng[c] * rsqrtf(bnv[c] + EPS_);
    w1f[n] = w1[c * 72 + ic * 9 + tp] * s;
  }
  if (n < 7168) {
    int nn = n % 28, c = n / 28;
    w2t[n] = (nn < 25) ? w2[nn * 256 + c] : 0.f;
  }
}

// ---------------------------------------------------------------- x fp32 NCHW -> xT bf16 NHWC
// + fused GAP partial sums (atomicAdd into partial[b*256+ch]; saves a full x re-read).
// grid: 256 px-tiles(64) x 8 b = 2048 blocks
__global__ __launch_bounds__(256) void transpose_kernel(const float* __restrict__ x,
                                                        unsigned short* __restrict__ xT,
                                                        float* __restrict__ partial) {
  int blk = blockIdx.x;
  int tile = blk & 255, b = blk >> 8;
  int px0 = tile * 64;
  __shared__ unsigned int tr[64 * 130];  // [px][128 ch-pair words + 2 pad]
  for (int i = threadIdx.x; i < 1024; i += 256) {
    int ch2 = i >> 3, pc = i & 7;
    const float* p0 = x + (((size_t)b * 256 + ch2 * 2) << 14) + px0 + pc * 8;
    const float4* a4 = (const float4*)p0;
    const float4* b4 = (const float4*)(p0 + 16384);
    float4 a0 = a4[0], a1 = a4[1], b0 = b4[0], b1 = b4[1];
    float fa[8] = {a0.x, a0.y, a0.z, a0.w, a1.x, a1.y, a1.z, a1.w};
    float fb[8] = {b0.x, b0.y, b0.z, b0.w, b1.x, b1.y, b1.z, b1.w};
    float sa = 0.f, sb = 0.f;
#pragma unroll
    for (int j = 0; j < 8; ++j) {
      sa += fa[j];
      sb += fb[j];
      unsigned int w = (unsigned int)f2bf(fa[j]) | ((unsigned int)f2bf(fb[j]) << 16);
      tr[(pc * 8 + j) * 130 + ch2] = w;
    }
    // 8-lane group reduce (lanes pc=0..7 share ch2), then one atomic per channel
    sa += __shfl_down(sa, 4, 8); sa += __shfl_down(sa, 2, 8); sa += __shfl_down(sa, 1, 8);
    sb += __shfl_down(sb, 4, 8); sb += __shfl_down(sb, 2, 8); sb += __shfl_down(sb, 1, 8);
    if ((threadIdx.x & 7) == 0) {
      atomicAdd(&partial[(b << 8) + ch2 * 2], sa);
      atomicAdd(&partial[(b << 8) + ch2 * 2 + 1], sb);
    }
  }
  __syncthreads();
  for (int i = threadIdx.x; i < 2048; i += 256) {
    int px = i >> 5, kc = i & 31;
    uint4 v = *(uint4*)&tr[px * 130 + kc * 4];
    *(uint4*)(xT + ((((size_t)b << 14)) + px0 + px) * 256 + kc * 8) = v;
  }
}

// ---------------------------------------------------------------- fused bodies
// kernelgen body: full image (8 ch-rounds) per block, softmax fused, writes kern.
// 512 blocks; grid-limited occupancy is cured by co-residency with conv blocks.
__device__ __forceinline__ void kernelgen_body(int kblk, const unsigned short* __restrict__ xT,
                                               const float* __restrict__ w1f,
                                               const float* __restrict__ b1f,
                                               const float* __restrict__ w2t,
                                               const float* __restrict__ b2,
                                               float* __restrict__ kern, char* smemc) {
  unsigned short* xs = (unsigned short*)smemc;  // [18x18 px][32 ch + 8 pad] = 25,920B
  int t = kblk & 63, b = kblk >> 6;
  int px0 = (t & 7) * 16, py0 = (t >> 3) * 16;
  int lx = threadIdx.x & 15, ly = threadIdx.x >> 4;
  float acc[25];
#pragma unroll
  for (int n = 0; n < 25; ++n) acc[n] = b2[n];

#pragma unroll 1
  for (int gq = 0; gq < 8; ++gq) {
    __syncthreads();
    for (int i = threadIdx.x; i < 1296; i += 256) {
      int s = i & 3, p = i >> 2;
      int yy = py0 + p / 18 - 1, xx = px0 + (p % 18) - 1;
      u16x8 v = (u16x8)(unsigned short)0;
      if (((unsigned)yy < 128u) && ((unsigned)xx < 128u))
        v = *(const u16x8*)(xT + (((size_t)(b << 14)) + yy * 128 + xx) * 256 + gq * 32 + s * 8);
      *(lds_u16x8*)(&xs[p * 40 + s * 8]) = v;
    }
    __syncthreads();
#pragma unroll
    for (int s = 0; s < 4; ++s) {
      int g = gq * 4 + s;
      const float* wg = w1f + g * 576;  // [tp][o][ic], wave-uniform -> s_load
      const float* bp = b1f + g * 8;
      float h[8];
#pragma unroll
      for (int o = 0; o < 8; ++o) h[o] = bp[o];
#pragma unroll
      for (int tp = 0; tp < 9; ++tp) {
        float xv[8];
        u16x8 v = *(lds_u16x8*)(&xs[((ly + tp / 3) * 18 + lx + tp % 3) * 40 + s * 8]);
        cvt8_(v, xv);
        const float* wt = wg + tp * 64;
#pragma unroll
        for (int o = 0; o < 8; ++o)
#pragma unroll
          for (int ic = 0; ic < 8; ++ic) h[o] = fmaf(xv[ic], wt[o * 8 + ic], h[o]);
      }
#pragma unroll
      for (int o = 0; o < 8; ++o) {
        float sv = h[o] * sigmoidf_(h[o]);
        const float* w2p = w2t + (g * 8 + o) * 28;  // 25 contiguous floats
#pragma unroll
        for (int n = 0; n < 25; ++n) acc[n] = fmaf(sv, w2p[n], acc[n]);
      }
    }
  }
  float m = acc[0];
#pragma unroll
  for (int n = 1; n < 25; ++n) m = fmaxf(m, acc[n]);
  float sum = 0.f;
#pragma unroll
  for (int n = 0; n < 25; ++n) { acc[n] = __expf(acc[n] - m); sum += acc[n]; }
  float inv = 1.f / sum;
  size_t base = (((size_t)b * 25) << 14) + (py0 + ly) * 128 + px0 + lx;
#pragma unroll
  for (int n = 0; n < 25; ++n) kern[base + ((size_t)n << 14)] = acc[n] * inv;
}

// conv body: M=128 px (one row) x N=128 oc; K = 24 rows (8 cb x 3 kh) x 32 ch.
// WAVE = 128px x 32oc (mt=8, nt=2): distinct oc band per wave (zero wT redundancy),
// direct f32x4 stores. ROW-PAIR RING-4 PIPELINE: per pair P: [vmcnt(6)] [barrier]
// [2 rows x 48 MFMA] [barrier] [stage 2 rows]. Swizzle s = k ^ ((px>>1)&3) on source.
// bid XCD-swizzle: each XCD gets 256 consecutive logical blocks (one batch image).
__device__ __forceinline__ void conv_body(int cblk, const unsigned short* __restrict__ xT,
                                          const unsigned short* __restrict__ wT,
                                          const float* __restrict__ bb,
                                          const float* __restrict__ bng,
                                          const float* __restrict__ bnb,
                                          const float* __restrict__ bnm,
                                          const float* __restrict__ bnv,
                                          const unsigned short* __restrict__ zbuf,
                                          float* __restrict__ out, char* smemc) {
  int nb = ((cblk & 7) << 8) | (cblk >> 3);  // XCD swizzle (2048 % 8 == 0)
  int ocb = nb & 1, y = (nb >> 1) & 127, b = nb >> 8;
  int lane = threadIdx.x & 63, wid = threadIdx.x >> 6;
  int m_l = lane & 15, kgrp = lane >> 4;

  unsigned short* xs = (unsigned short*)smemc;  // ring: 4 x 8320B row slots
  const char* zc = (const char*)zbuf;

  // per-thread staging constants: wave w covers granules [w*130, w*130+130)
  int g0 = wid * 130 + lane, g1 = g0 + 64, g2 = wid * 130 + 128 + lane;  // g2: lane<2
  int px0_ = g0 >> 2, k0_ = g0 & 3, s0_ = k0_ ^ ((px0_ >> 1) & 3), gx0 = px0_ - 1;
  int px1_ = g1 >> 2, k1_ = g1 & 3, s1_ = k1_ ^ ((px1_ >> 1) & 3), gx1 = px1_ - 1;
  int px2_ = g2 >> 2, k2_ = g2 & 3, s2_ = k2_ ^ ((px2_ >> 1) & 3), gx2 = px2_ - 1;
  bool ok0 = (unsigned)gx0 < 128u, ok1 = (unsigned)gx1 < 128u, ok2 = (unsigned)gx2 < 128u;
  int off0 = gx0 * 512 + s0_ * 16, off1 = gx1 * 512 + s1_ * 16, off2 = gx2 * 512 + s2_ * 16;
  int d0 = (wid * 130) * 16, d1 = d0 + 1024, d2 = d0 + 2048;  // wave-uniform LDS bases

#define STAGE_ROW(slotB_, cbn_, khn_)                                                       \
  do {                                                                                      \
    int gy_ = y + (khn_)-1;                                                                 \
    bool gyok_ = ((unsigned)gy_ < 128u);                                                    \
    const char* rb_ =                                                                       \
        (const char*)xT + (((size_t)b << 14) + (size_t)(gy_ & 127) * 128) * 512 + (cbn_)*64;\
    gload16((gyok_ && ok0) ? rb_ + off0 : zc, smemc + (slotB_) + d0);                       \
    gload16((gyok_ && ok1) ? rb_ + off1 : zc, smemc + (slotB_) + d1);                       \
    if (lane < 2) gload16((gyok_ && ok2) ? rb_ + off2 : zc, smemc + (slotB_) + d2);         \
  } while (0)

  f32x4 acc[8][2];
#pragma unroll
  for (int mt = 0; mt < 8; ++mt)
#pragma unroll
    for (int nt = 0; nt < 2; ++nt) acc[mt][nt] = (f32x4)0.f;

  // prologue: stage rows 0..3 (row r -> cb=r/3, kh=r%3, slot r&3)
  STAGE_ROW(0, 0, 0);
  STAGE_ROW(8320, 0, 1);
  STAGE_ROW(16640, 0, 2);
  STAGE_ROW(24960, 1, 0);

  // per-thread bfrag base (ushorts); wave owns oc band [ocb*128 + wid*32, +32)
  int oc0 = ocb * 128 + wid * 32;
  const unsigned short* wTb = wT + ((size_t)(oc0 + m_l) * 32 + kgrp * 8);
  int khn = 1, cbn = 1;  // next row to stage = 4 -> cb1,kh1

#pragma unroll 1
  for (int P = 0; P < 12; ++P) {
    if (P < 11) {
      asm volatile("s_waitcnt vmcnt(6)" ::: "memory");  // rows 2P,2P+1 landed
    } else {
      asm volatile("s_waitcnt vmcnt(0)" ::: "memory");
    }
    __builtin_amdgcn_s_barrier();
    asm volatile("" ::: "memory");
    __builtin_amdgcn_s_setprio(1);
#pragma unroll
    for (int half = 0; half < 2; ++half) {
      int R = 2 * P + half;
      const unsigned short* xb = xs + (R & 3) * 4160;
#pragma unroll
      for (int kw = 0; kw < 3; ++kw) {
        bf16x8 bfrag[2];
        const unsigned short* wb = wTb + (size_t)(R * 3 + kw) * 8192;
#pragma unroll
        for (int nt = 0; nt < 2; ++nt) bfrag[nt] = *(const bf16x8*)(wb + nt * 512);
#pragma unroll
        for (int mt = 0; mt < 8; ++mt) {
          int apx = mt * 16 + m_l + kw;
          int kk = kgrp ^ ((apx >> 1) & 3);
          bf16x8 af =
              *(__attribute__((address_space(3))) bf16x8*)(&xb[apx * 32 + kk * 8]);
#pragma unroll
          for (int nt = 0; nt < 2; ++nt)
            acc[mt][nt] =
                __builtin_amdgcn_mfma_f32_16x16x32_bf16(af, bfrag[nt], acc[mt][nt], 0, 0, 0);
        }
      }
    }
    __builtin_amdgcn_s_setprio(0);
    __builtin_amdgcn_s_barrier();  // slots (2P)&3, (2P+1)&3 free
    asm volatile("" ::: "memory");
    if (P < 10) {
      STAGE_ROW((size_t)((2 * P + 4) & 3) * 8320, cbn, khn);
      ++khn;
      if (khn == 3) { khn = 0; ++cbn; }
      STAGE_ROW((size_t)((2 * P + 5) & 3) * 8320, cbn, khn);
      ++khn;
      if (khn == 3) { khn = 0; ++cbn; }
    }
  }
#undef STAGE_ROW

  // epilogue: direct stores — wave owns oc rows [oc0, oc0+32), all 128 px.
  float scale2[2], bias2[2];
#pragma unroll
  for (int nt = 0; nt < 2; ++nt) {
    int oc = oc0 + nt * 16 + m_l;
    float s = bng[oc] * rsqrtf(bnv[oc] + EPS_);
    scale2[nt] = s;
    bias2[nt] = bnb[oc] + (bb[oc] - bnm[oc]) * s;
  }
#pragma unroll
  for (int nt = 0; nt < 2; ++nt) {
    size_t obase = (((size_t)(b * 256 + oc0 + nt * 16 + m_l)) << 14) + y * 128 + kgrp * 4;
#pragma unroll
    for (int mt = 0; mt < 8; ++mt) {
      f32x4 v = acc[mt][nt];
      float o4[4];
#pragma unroll
      for (int r = 0; r < 4; ++r) {
        float hv = v[r] * scale2[nt] + bias2[nt];
        o4[r] = hv * sigmoidf_(hv);
      }
      *(f32x4*)(out + obase + mt * 16) = (f32x4){o4[0], o4[1], o4[2], o4[3]};
    }
  }
}

// ---------------------------------------------------------------- fused dispatch
// blocks [0,kgN) run kernelgen (VALU-bound), the rest run conv (MFMA-bound).
// Co-resident VALU-heavy and MFMA-heavy waves share each CU's independent pipes
// (m114: co-schedule ~ max, not sum). kernelgen first: all 512 resident from t=0.
__global__ __launch_bounds__(256, 4) void fused_kernel(
    int kgN, const unsigned short* __restrict__ xT, const unsigned short* __restrict__ wT,
    const float* __restrict__ w1f, const float* __restrict__ b1f, const float* __restrict__ w2t,
    const float* __restrict__ b2, float* __restrict__ kern, const float* __restrict__ bb,
    const float* __restrict__ bng, const float* __restrict__ bnb, const float* __restrict__ bnm,
    const float* __restrict__ bnv, const unsigned short* __restrict__ zbuf,
    float* __restrict__ out) {
  __shared__ char smem[33280];  // conv ring (33,280B); kernelgen uses first 25,920B
  int blk = (int)blockIdx.x;
  if (blk < kgN) {
    kernelgen_body(blk, xT, w1f, b1f, w2t, b2, kern, smem);
  } else {
    conv_body(blk - kgN, xT, wT, bb, bng, bnb, bnm, bnv, zbuf, out, smem);
  }
}

// ---------------------------------------------------------------- CARAFE + blend (RMW on out)
// grid: 16 ch-groups x 8 bx x 4 by x 8 b = 4096 blocks; tile 16ch x 32y x 16x
__global__ __launch_bounds__(256) void carafe_blend_kernel(
    const unsigned short* __restrict__ xT, const float* __restrict__ kern,
    const float* __restrict__ gq, float* __restrict__ out) {
  int blk = blockIdx.x;
  int ocg = blk & 15, bx = (blk >> 4) & 7, by = (blk >> 7) & 3, b = blk >> 9;
  __shared__ unsigned short xc[720 * 16];  // [36x20 px][16 ch]
  for (int i = threadIdx.x; i < 1440; i += 256) {
    int half = i & 1, p = i >> 1;
    int py = p / 20, pxx = p - py * 20;
    int yy = by * 32 + py - 2, xx = bx * 16 + pxx - 2;
    yy = yy < 0 ? -yy : (yy > 127 ? 254 - yy : yy);
    xx = xx < 0 ? -xx : (xx > 127 ? 254 - xx : xx);
    *(lds_u16x8*)(&xc[p * 16 + half * 8]) =
        *(const u16x8*)(xT + (((size_t)(b << 14)) + yy * 128 + xx) * 256 + ocg * 16 + half * 8);
  }
  __syncthreads();
  int lx = threadIdx.x & 15, y0 = (threadIdx.x >> 4) * 2;
  float gv = gq[b];
  int gy0 = by * 32 + y0, gx = bx * 16 + lx;
  float kv0[25], kv1[25];
  size_t kb = (((size_t)b * 25) << 14) + gy0 * 128 + gx;
#pragma unroll
  for (int n = 0; n < 25; ++n) {
    kv0[n] = kern[kb + ((size_t)n << 14)];
    kv1[n] = kern[kb + ((size_t)n << 14) + 128];
  }
  float car0[16], car1[16];
#pragma unroll
  for (int c = 0; c < 16; ++c) { car0[c] = 0.f; car1[c] = 0.f; }
#pragma unroll
  for (int n = 0; n < 25; ++n) {
    int ki = n / 5, kj = n - ki * 5;
    int p0 = (y0 + ki) * 20 + lx + kj;
    float f0[16], f1[16];
    cvt8_(*(lds_u16x8*)(&xc[p0 * 16]), &f0[0]);
    cvt8_(*(lds_u16x8*)(&xc[p0 * 16 + 8]), &f0[8]);
    cvt8_(*(lds_u16x8*)(&xc[(p0 + 20) * 16]), &f1[0]);
    cvt8_(*(lds_u16x8*)(&xc[(p0 + 20) * 16 + 8]), &f1[8]);
#pragma unroll
    for (int c = 0; c < 16; ++c) {
      car0[c] = fmaf(f0[c], kv0[n], car0[c]);
      car1[c] = fmaf(f1[c], kv1[n], car1[c]);
    }
  }
#pragma unroll
  for (int c = 0; c < 16; ++c) {
    size_t ob = (((size_t)(b * 256 + ocg * 16 + c)) << 14) + gy0 * 128 + gx;
    float st0 = out[ob], st1 = out[ob + 128];
    out[ob] = fmaf(gv, car0[c] - st0, st0);
    out[ob + 128] = fmaf(gv, car1[c] - st1, st1);
  }
}

// ---------------------------------------------------------------- launcher
extern "C" void kernel_launch(void* const* d_in, const int* in_sizes, int n_in,
                              void* d_out, int out_size, void* d_ws, size_t ws_size,
                              hipStream_t stream) {
  const float* x      = (const float*)d_in[0];
  const float* ke_w1  = (const float*)d_in[1];
  const float* ke_b1  = (const float*)d_in[2];
  const float* ke_bng = (const float*)d_in[3];
  const float* ke_bnb = (const float*)d_in[4];
  const float* ke_bnm = (const float*)d_in[5];
  const float* ke_bnv = (const float*)d_in[6];
  const float* ke_w2  = (const float*)d_in[7];
  const float* ke_b2  = (const float*)d_in[8];
  const float* bs_w   = (const float*)d_in[9];
  const float* bs_b   = (const float*)d_in[10];
  const float* bs_bng = (const float*)d_in[11];
  const float* bs_bnb = (const float*)d_in[12];
  const float* bs_bnm = (const float*)d_in[13];
  const float* bs_bnv = (const float*)d_in[14];
  const float* g_w    = (const float*)d_in[15];
  const float* g_b    = (const float*)d_in[16];
  float* outp = (float*)d_out;

  char* ws = (char*)d_ws;
  float* kern        = (float*)(ws);                      // 13,107,200 B
  float* partial     = (float*)(ws + 13107200);           // 8,192 B
  float* gout        = (float*)(ws + 13115392);           // bytes 0-31 of 256B slot
  float* zbuff       = (float*)(ws + 13115392 + 128);     // 64B zero pad
  unsigned short* wT = (unsigned short*)(ws + 13115648);  // 1,179,648 B
  unsigned short* xT = (unsigned short*)(ws + 14295296);  // 67,108,864 B -> 81,404,160 total

  // kprep tables (103,424 B): prefer ws tail (enables fused launch: conv writes out
  // concurrently, so tables must NOT alias d_out). If ws is too small, fall back to
  // dead d_out space + serial launches (R8 semantics).
  const size_t USED = 81404160;
  bool bigws = ws_size >= USED + 131072;
  float *w1f, *b1f, *w2t;
  if (bigws) {
    w1f = (float*)(ws + USED);            // 73,728 B
    b1f = (float*)(ws + USED + 73728);    //  1,024 B
    w2t = (float*)(ws + USED + 74752);    // 28,672 B
  } else {
    w1f = (float*)((char*)d_out + 52428800);
    b1f = (float*)((char*)d_out + 52502528);
    w2t = (float*)((char*)d_out + 52503552);
  }

  hipMemsetAsync(partial, 0, 2048 * sizeof(float), stream);  // GAP accumulators
  kprep_kernel<<<72, 256, 0, stream>>>(ke_w1, ke_b1, ke_bng, ke_bnb, ke_bnm, ke_bnv, ke_w2,
                                       w1f, b1f, w2t, zbuff);
  wtrans_kernel<<<2304, 256, 0, stream>>>(bs_w, wT);
  transpose_kernel<<<2048, 256, 0, stream>>>(x, xT, partial);
  gate_kernel<<<8, 256, 0, stream>>>(partial, g_w, g_b, gout);

  if (bigws) {
    // fused: 512 kernelgen blocks (first, all co-resident) + 2048 conv blocks
    fused_kernel<<<2560, 256, 0, stream>>>(512, xT, wT, w1f, b1f, w2t, ke_b2, kern, bs_b,
                                           bs_bng, bs_bnb, bs_bnm, bs_bnv,
                                           (const unsigned short*)zbuff, outp);
  } else {
    // serial fallback: tables live in d_out (dead until conv runs after kernelgen)
    fused_kernel<<<512, 256, 0, stream>>>(512, xT, wT, w1f, b1f, w2t, ke_b2, kern, bs_b,
                                          bs_bng, bs_bnb, bs_bnm, bs_bnv,
                                          (const unsigned short*)zbuff, outp);
    fused_kernel<<<2048, 256, 0, stream>>>(0, xT, wT, w1f, b1f, w2t, ke_b2, kern, bs_b,
                                           bs_bng, bs_bnb, bs_bnm, bs_bnv,
                                           (const unsigned short*)zbuff, outp);
  }
  carafe_blend_kernel<<<4096, 256, 0, stream>>>(xT, kern, gout, outp);
}